// Round 1
// baseline (4556.976 us; speedup 1.0000x reference)
//
#include <hip/hip_runtime.h>
#include <math.h>

#define N_NODES 50000
#define N_EDGES 640000
#define INF_ 64
#define DD 96
#define HH 384
#define NLAYERS 4
#define NGRAPH 512
#define NOUT_ 2

#define ACT_NONE 0
#define ACT_RELU 1
#define ACT_ELU 2
#define ACT_LEAKY 3

// ---------------- generic fp32 tiled GEMM: C = act(A@B (+bias) (+C)) ----------------
// A: M x K row-major.  B: K x Nc (or Nc x K if TRANSB).  K must be a multiple of 16.
template<int ACT, bool TRANSB, bool ACCUM>
__global__ __launch_bounds__(256)
void gemm_k(const float* __restrict__ A, const float* __restrict__ B,
            const float* __restrict__ bias, float* __restrict__ C,
            int M, int Nc, int K)
{
    const int BM = 64, BN = 64, BK = 16;
    __shared__ float As[BK][BM + 4];
    __shared__ float Bs[BK][BN + 4];
    int tid = threadIdx.x;
    int tx = tid & 15, ty = tid >> 4;
    int bm0 = blockIdx.x * BM, bn0 = blockIdx.y * BN;
    float acc[4][4] = {};
    for (int k0 = 0; k0 < K; k0 += BK) {
        #pragma unroll
        for (int i = 0; i < 4; i++) {
            int idx = i * 256 + tid;
            int k = idx & 15, m = idx >> 4;
            int row = bm0 + m;
            As[k][m] = (row < M) ? A[(size_t)row * K + k0 + k] : 0.f;
        }
        #pragma unroll
        for (int i = 0; i < 4; i++) {
            int idx = i * 256 + tid;
            if (!TRANSB) {
                int n = idx & 63, k = idx >> 6;
                int col = bn0 + n;
                Bs[k][n] = (col < Nc) ? B[(size_t)(k0 + k) * Nc + col] : 0.f;
            } else {
                int k = idx & 15, n = idx >> 4;
                int col = bn0 + n;
                Bs[k][n] = (col < Nc) ? B[(size_t)col * K + k0 + k] : 0.f;
            }
        }
        __syncthreads();
        #pragma unroll
        for (int k = 0; k < BK; k++) {
            float a[4], b[4];
            #pragma unroll
            for (int i = 0; i < 4; i++) a[i] = As[k][ty * 4 + i];
            #pragma unroll
            for (int j = 0; j < 4; j++) b[j] = Bs[k][tx * 4 + j];
            #pragma unroll
            for (int i = 0; i < 4; i++)
                #pragma unroll
                for (int j = 0; j < 4; j++)
                    acc[i][j] += a[i] * b[j];
        }
        __syncthreads();
    }
    #pragma unroll
    for (int i = 0; i < 4; i++) {
        int row = bm0 + ty * 4 + i;
        if (row >= M) continue;
        #pragma unroll
        for (int j = 0; j < 4; j++) {
            int col = bn0 + tx * 4 + j;
            if (col >= Nc) continue;
            float v = acc[i][j];
            if (bias) v += bias[col];
            if (ACCUM) v += C[(size_t)row * Nc + col];
            if (ACT == ACT_RELU)       v = v > 0.f ? v : 0.f;
            else if (ACT == ACT_ELU)   v = v > 0.f ? v : expm1f(v);
            else if (ACT == ACT_LEAKY) v = v > 0.f ? v : 0.01f * v;
            C[(size_t)row * Nc + col] = v;
        }
    }
}

__device__ __forceinline__ float wave_reduce_sum(float v)
{
    #pragma unroll
    for (int o = 32; o > 0; o >>= 1) v += __shfl_xor(v, o, 64);
    return v;
}

// ---------------- LayerNorm: out = LN(a (+b)) * g + beta, one wave per row ----------------
template<int RL>
__global__ __launch_bounds__(256)
void ln_k(const float* __restrict__ a, const float* __restrict__ b,
          const float* __restrict__ g, const float* __restrict__ beta,
          float* __restrict__ out, int M)
{
    int wave = threadIdx.x >> 6;
    int lane = threadIdx.x & 63;
    int row = blockIdx.x * 4 + wave;
    if (row >= M) return;
    const int NE = (RL + 63) / 64;
    float vals[NE];
    float s = 0.f;
    #pragma unroll
    for (int i = 0; i < NE; i++) {
        int j = lane + i * 64;
        float x = 0.f;
        if (j < RL) {
            x = a[(size_t)row * RL + j];
            if (b) x += b[(size_t)row * RL + j];
        }
        vals[i] = x; s += x;
    }
    s = wave_reduce_sum(s);
    float mean = s / RL;
    float sq = 0.f;
    #pragma unroll
    for (int i = 0; i < NE; i++) {
        int j = lane + i * 64;
        if (j < RL) { float d = vals[i] - mean; sq += d * d; }
    }
    sq = wave_reduce_sum(sq);
    float rstd = rsqrtf(sq / RL + 1e-5f);
    #pragma unroll
    for (int i = 0; i < NE; i++) {
        int j = lane + i * 64;
        if (j < RL) out[(size_t)row * RL + j] = (vals[i] - mean) * rstd * g[j] + beta[j];
    }
}

// ---------------- edge pass 1: ae = exp(scale*(Q[d]·Kn[s] + Qk[d]·ea[e])); denom[s] += ae ----------------
__global__ __launch_bounds__(256)
void edge1_k(const float* __restrict__ Q, const float* __restrict__ Kn,
             const float* __restrict__ Qk, const float* __restrict__ ea,
             const int* __restrict__ src, const int* __restrict__ dst,
             float* __restrict__ ae, float* __restrict__ denom, float scale)
{
    int e = blockIdx.x * 16 + (threadIdx.x >> 4);
    int lane = threadIdx.x & 15;
    if (e >= N_EDGES) return;
    int s = src[e], d = dst[e];
    float dot = 0.f;
    #pragma unroll
    for (int i = 0; i < 6; i++) {
        int j = lane + i * 16;
        dot += Q[(size_t)d * DD + j] * Kn[(size_t)s * DD + j]
             + Qk[(size_t)d * DD + j] * ea[(size_t)e * DD + j];
    }
    #pragma unroll
    for (int o = 8; o > 0; o >>= 1) dot += __shfl_xor(dot, o, 16);
    if (lane == 0) {
        float v = expf(dot * scale);
        ae[e] = v;
        atomicAdd(&denom[s], v);
    }
}

// ---------------- edge pass 2: w = ae/denom[s]; agg[d] += w*V[s]; T[d] += w*ea[e] ----------------
__global__ __launch_bounds__(256)
void edge2_k(const float* __restrict__ V, const float* __restrict__ ea,
             const float* __restrict__ aev, const float* __restrict__ denom,
             const int* __restrict__ src, const int* __restrict__ dst,
             float* __restrict__ agg, float* __restrict__ T)
{
    int e = blockIdx.x * 16 + (threadIdx.x >> 4);
    int lane = threadIdx.x & 15;
    if (e >= N_EDGES) return;
    int s = src[e], d = dst[e];
    float w = aev[e] / denom[s];
    #pragma unroll
    for (int i = 0; i < 6; i++) {
        int j = lane + i * 16;
        atomicAdd(&agg[(size_t)d * DD + j], w * V[(size_t)s * DD + j]);
        atomicAdd(&T[(size_t)d * DD + j],   w * ea[(size_t)e * DD + j]);
    }
}

// ---------------- mean-pool scatter ----------------
__global__ __launch_bounds__(256)
void pool_k(const float* __restrict__ u, const int* __restrict__ batch,
            float* __restrict__ pooled, float* __restrict__ cnt)
{
    int n = blockIdx.x * 4 + (threadIdx.x >> 6);
    int lane = threadIdx.x & 63;
    if (n >= N_NODES) return;
    int bg = batch[n];
    #pragma unroll
    for (int i = 0; i < 6; i++) {
        int j = lane + i * 64;
        atomicAdd(&pooled[(size_t)bg * HH + j], u[(size_t)n * HH + j]);
    }
    if (lane == 0) atomicAdd(&cnt[bg], 1.f);
}

// ---------------- classifier head: out = (pooled/cnt) @ clf_W + clf_b ----------------
__global__ __launch_bounds__(64)
void clf_k(const float* __restrict__ pooled, const float* __restrict__ cnt,
           const float* __restrict__ W, const float* __restrict__ bcl,
           float* __restrict__ out)
{
    int g = blockIdx.x;
    int lane = threadIdx.x;
    float c = cnt[g]; c = c > 1.f ? c : 1.f;
    float inv = 1.f / c;
    float a0 = 0.f, a1 = 0.f;
    #pragma unroll
    for (int i = 0; i < 6; i++) {
        int j = lane + i * 64;
        float pv = pooled[(size_t)g * HH + j] * inv;
        a0 += pv * W[j * 2 + 0];
        a1 += pv * W[j * 2 + 1];
    }
    a0 = wave_reduce_sum(a0);
    a1 = wave_reduce_sum(a1);
    if (lane == 0) {
        out[g * 2 + 0] = a0 + bcl[0];
        out[g * 2 + 1] = a1 + bcl[1];
    }
}

extern "C" void kernel_launch(void* const* d_in, const int* in_sizes, int n_in,
                              void* d_out, int out_size, void* d_ws, size_t ws_size,
                              hipStream_t stream)
{
    const float* x       = (const float*)d_in[0];
    const float* ea      = (const float*)d_in[1];
    const float* emb_W1  = (const float*)d_in[2];
    const float* emb_b1  = (const float*)d_in[3];
    const float* emb_W2  = (const float*)d_in[4];
    const float* emb_b2  = (const float*)d_in[5];
    const float* Wq      = (const float*)d_in[6];
    const float* Wk      = (const float*)d_in[7];
    const float* Wv      = (const float*)d_in[8];
    const float* ffn_W1  = (const float*)d_in[9];
    const float* ffn_W2  = (const float*)d_in[10];
    const float* bq      = (const float*)d_in[11];
    const float* bk      = (const float*)d_in[12];
    const float* bv      = (const float*)d_in[13];
    const float* ffn_b1  = (const float*)d_in[14];
    const float* ffn_b2  = (const float*)d_in[15];
    const float* n1_b    = (const float*)d_in[16];
    const float* n2_b    = (const float*)d_in[17];
    const float* n1_g    = (const float*)d_in[18];
    const float* n2_g    = (const float*)d_in[19];
    const float* u_W1    = (const float*)d_in[20];
    const float* u_b1    = (const float*)d_in[21];
    const float* u_W2    = (const float*)d_in[22];
    const float* u_b2    = (const float*)d_in[23];
    const float* u_g     = (const float*)d_in[24];
    const float* u_bb    = (const float*)d_in[25];
    const float* clf_W   = (const float*)d_in[26];
    const float* clf_b   = (const float*)d_in[27];
    const float* rec_W1  = (const float*)d_in[28];
    const float* rec_b1  = (const float*)d_in[29];
    const float* rec_W2  = (const float*)d_in[30];
    const float* rec_b2  = (const float*)d_in[31];
    const int* edge_index = (const int*)d_in[32];
    const int* batch     = (const int*)d_in[33];
    const int* srcI = edge_index;
    const int* dstI = edge_index + N_EDGES;

    float* out   = (float*)d_out;
    float* r_out = out + NGRAPH * NOUT_;

    // workspace carve-up (~176 MB)
    float* p = (float*)d_ws;
    float* h      = p; p += (size_t)N_NODES * DD;
    float* bufH1  = p; p += (size_t)N_NODES * HH;
    float* bufH2  = p; p += (size_t)N_NODES * HH;
    float* aeBuf  = p; p += N_EDGES;
    float* denom  = p; p += N_NODES;
    float* pooled = p; p += NGRAPH * HH;
    float* cnt    = p; p += NGRAPH;

    dim3 blk(256);
    auto ggrid = [](int M, int Nc) { return dim3((M + 63) / 64, (Nc + 63) / 64); };
    const float scale = 1.f / sqrtf((float)DD);

    // ---- atom embedding MLP ----
    gemm_k<ACT_RELU, false, false><<<ggrid(N_NODES, HH), blk, 0, stream>>>(
        x, emb_W1, emb_b1, bufH1, N_NODES, HH, INF_);
    gemm_k<ACT_NONE, false, false><<<ggrid(N_NODES, DD), blk, 0, stream>>>(
        bufH1, emb_W2, emb_b2, h, N_NODES, DD, HH);

    // ---- RPETConv layers ----
    for (int l = 0; l < NLAYERS; l++) {
        const float* Wq_l = Wq + (size_t)l * DD * DD;
        const float* Wk_l = Wk + (size_t)l * DD * DD;
        const float* Wv_l = Wv + (size_t)l * DD * DD;
        const float* W1_l = ffn_W1 + (size_t)l * DD * DD;
        const float* W2_l = ffn_W2 + (size_t)l * DD * DD;
        const float* bq_l = bq + (size_t)l * DD;
        const float* bk_l = bk + (size_t)l * DD;
        const float* bv_l = bv + (size_t)l * DD;
        const float* b1_l = ffn_b1 + (size_t)l * DD;
        const float* b2_l = ffn_b2 + (size_t)l * DD;

        float* Qb  = bufH2;
        float* Kb  = bufH2 + (size_t)N_NODES * DD;
        float* Vb  = bufH2 + 2 * (size_t)N_NODES * DD;
        float* Qkb = bufH2 + 3 * (size_t)N_NODES * DD;

        gemm_k<ACT_NONE, false, false><<<ggrid(N_NODES, DD), blk, 0, stream>>>(
            h, Wq_l, bq_l, Qb, N_NODES, DD, DD);
        gemm_k<ACT_NONE, false, false><<<ggrid(N_NODES, DD), blk, 0, stream>>>(
            h, Wk_l, bk_l, Kb, N_NODES, DD, DD);
        gemm_k<ACT_NONE, false, false><<<ggrid(N_NODES, DD), blk, 0, stream>>>(
            h, Wv_l, bv_l, Vb, N_NODES, DD, DD);
        // Qk = Q @ Wk^T
        gemm_k<ACT_NONE, true, false><<<ggrid(N_NODES, DD), blk, 0, stream>>>(
            Qb, Wk_l, nullptr, Qkb, N_NODES, DD, DD);

        hipMemsetAsync(denom, 0, N_NODES * sizeof(float), stream);
        edge1_k<<<(N_EDGES + 15) / 16, blk, 0, stream>>>(
            Qb, Kb, Qkb, ea, srcI, dstI, aeBuf, denom, scale);

        float* agg = Qb;   // Q dead after pass 1
        float* T   = Kb;   // K dead after pass 1 (contiguous with agg)
        hipMemsetAsync(agg, 0, 2 * (size_t)N_NODES * DD * sizeof(float), stream);
        edge2_k<<<(N_EDGES + 15) / 16, blk, 0, stream>>>(
            Vb, ea, aeBuf, denom, srcI, dstI, agg, T);

        // agg += T @ Wv
        gemm_k<ACT_NONE, false, true><<<ggrid(N_NODES, DD), blk, 0, stream>>>(
            T, Wv_l, nullptr, agg, N_NODES, DD, DD);

        float* h1 = Qkb;   // Qk dead
        ln_k<DD><<<(N_NODES + 3) / 4, blk, 0, stream>>>(
            h, agg, n1_g + (size_t)l * DD, n1_b + (size_t)l * DD, h1, N_NODES);

        // FFN
        gemm_k<ACT_ELU, false, false><<<ggrid(N_NODES, DD), blk, 0, stream>>>(
            h1, W1_l, b1_l, Vb, N_NODES, DD, DD);
        gemm_k<ACT_NONE, false, false><<<ggrid(N_NODES, DD), blk, 0, stream>>>(
            Vb, W2_l, b2_l, agg, N_NODES, DD, DD);
        ln_k<DD><<<(N_NODES + 3) / 4, blk, 0, stream>>>(
            agg, h1, n2_g + (size_t)l * DD, n2_b + (size_t)l * DD, h, N_NODES);
    }

    // ---- updim + LN ----
    gemm_k<ACT_LEAKY, false, false><<<ggrid(N_NODES, HH), blk, 0, stream>>>(
        h, u_W1, u_b1, bufH2, N_NODES, HH, DD);
    gemm_k<ACT_NONE, false, false><<<ggrid(N_NODES, HH), blk, 0, stream>>>(
        bufH2, u_W2, u_b2, bufH1, N_NODES, HH, HH);
    ln_k<HH><<<(N_NODES + 3) / 4, blk, 0, stream>>>(
        bufH1, nullptr, u_g, u_bb, bufH1, N_NODES);

    // ---- mean pool + classifier ----
    hipMemsetAsync(pooled, 0, (size_t)(NGRAPH * HH + NGRAPH) * sizeof(float), stream);
    pool_k<<<(N_NODES + 3) / 4, blk, 0, stream>>>(bufH1, batch, pooled, cnt);
    clf_k<<<NGRAPH, 64, 0, stream>>>(pooled, cnt, clf_W, clf_b, out);

    // ---- reconstruction head ----
    gemm_k<ACT_RELU, false, false><<<ggrid(N_NODES, HH), blk, 0, stream>>>(
        bufH1, rec_W1, rec_b1, bufH2, N_NODES, HH, HH);
    gemm_k<ACT_NONE, false, false><<<ggrid(N_NODES, INF_), blk, 0, stream>>>(
        bufH2, rec_W2, rec_b2, r_out, N_NODES, INF_, HH);
}

// Round 2
// 3135.522 us; speedup vs baseline: 1.4533x; 1.4533x over previous
//
#include <hip/hip_runtime.h>
#include <math.h>

#define N_NODES 50000
#define N_EDGES 640000
#define INF_ 64
#define DD 96
#define HH 384
#define NLAYERS 4
#define NGRAPH 512
#define NOUT_ 2
#define MAXDEG 64

#define ACT_NONE 0
#define ACT_RELU 1
#define ACT_ELU 2
#define ACT_LEAKY 3

// ---------------- fp32 tiled GEMM: C = act(A@B (+bias) (+C)) ----------------
// A: M x K row-major. B: K x Nc (or Nc x K if TRANSB). Requires BN | Nc, BK | K.
template<int BM, int BN, int BK, int TM, int TN, int ACT, bool TRANSB, bool ACCUM>
__global__ __launch_bounds__(256)
void gemm2(const float* __restrict__ A, const float* __restrict__ B,
           const float* __restrict__ bias, float* __restrict__ C,
           int M, int Nc, int K)
{
    __shared__ float As[BK][BM + 4];
    __shared__ float Bs[BK][BN + 4];
    const int TX = BN / TN;
    int tid = threadIdx.x;
    int tx = tid % TX, ty = tid / TX;
    int bm0 = blockIdx.x * BM, bn0 = blockIdx.y * BN;
    float acc[TM][TN] = {};
    for (int k0 = 0; k0 < K; k0 += BK) {
        // A tile (BM x BK) -> As transposed, float4 along K
        for (int idx = tid; idx < BM * BK / 4; idx += 256) {
            int m = idx / (BK / 4);
            int kk = (idx % (BK / 4)) * 4;
            int row = bm0 + m;
            float4 v = make_float4(0.f, 0.f, 0.f, 0.f);
            if (row < M) v = *(const float4*)&A[(size_t)row * K + k0 + kk];
            As[kk + 0][m] = v.x; As[kk + 1][m] = v.y;
            As[kk + 2][m] = v.z; As[kk + 3][m] = v.w;
        }
        if (!TRANSB) {
            for (int idx = tid; idx < BK * BN / 4; idx += 256) {
                int kk = idx / (BN / 4);
                int nn = (idx % (BN / 4)) * 4;
                *(float4*)&Bs[kk][nn] =
                    *(const float4*)&B[(size_t)(k0 + kk) * Nc + bn0 + nn];
            }
        } else {
            for (int idx = tid; idx < BK * BN; idx += 256) {
                int n = idx / BK, kk = idx % BK;
                Bs[kk][n] = B[(size_t)(bn0 + n) * K + k0 + kk];
            }
        }
        __syncthreads();
        #pragma unroll
        for (int k = 0; k < BK; k++) {
            float a[TM], b[TN];
            #pragma unroll
            for (int i = 0; i < TM; i++) a[i] = As[k][ty * TM + i];
            #pragma unroll
            for (int j = 0; j < TN; j++) b[j] = Bs[k][tx * TN + j];
            #pragma unroll
            for (int i = 0; i < TM; i++)
                #pragma unroll
                for (int j = 0; j < TN; j++)
                    acc[i][j] += a[i] * b[j];
        }
        __syncthreads();
    }
    #pragma unroll
    for (int i = 0; i < TM; i++) {
        int row = bm0 + ty * TM + i;
        if (row >= M) continue;
        #pragma unroll
        for (int j = 0; j < TN; j++) {
            int col = bn0 + tx * TN + j;
            float v = acc[i][j];
            if (bias) v += bias[col];
            if (ACCUM) v += C[(size_t)row * Nc + col];
            if (ACT == ACT_RELU)       v = fmaxf(v, 0.f);
            else if (ACT == ACT_ELU)   v = v > 0.f ? v : expm1f(v);
            else if (ACT == ACT_LEAKY) v = v > 0.f ? v : 0.01f * v;
            C[(size_t)row * Nc + col] = v;
        }
    }
}

__device__ __forceinline__ float wave_reduce_sum(float v)
{
    #pragma unroll
    for (int o = 32; o > 0; o >>= 1) v += __shfl_xor(v, o, 64);
    return v;
}

__device__ __forceinline__ float g32sum(float v)
{
    #pragma unroll
    for (int o = 16; o > 0; o >>= 1) v += __shfl_xor(v, o, 64);
    return v;
}

// ---------------- adjacency build (padded slots, no scan) ----------------
__global__ __launch_bounds__(256)
void scatter_k(const int* __restrict__ src, const int* __restrict__ dst,
               int* __restrict__ deg, int2* __restrict__ pe)
{
    int e = blockIdx.x * 256 + threadIdx.x;
    if (e >= N_EDGES) return;
    int d = dst[e];
    int c = atomicAdd(&deg[d], 1);
    if (c < MAXDEG) pe[(size_t)d * MAXDEG + c] = make_int2(src[e], e);
}

// ---------------- edge pass 1 (gather by dst): ae=exp(scale*(Q[d]·Kn[s]+Qk[d]·ea[e])) ----------------
__global__ __launch_bounds__(256)
void edge1c(const float* __restrict__ Q, const float* __restrict__ Kn,
            const float* __restrict__ Qk, const float* __restrict__ ea,
            const int2* __restrict__ pe, const int* __restrict__ deg,
            float* __restrict__ ae_slot, float* __restrict__ denom, float scale)
{
    int grp = threadIdx.x >> 5, lane = threadIdx.x & 31;
    int d = blockIdx.x * 8 + grp;
    if (d >= N_NODES) return;
    float q0 = Q[(size_t)d * DD + lane];
    float q1 = Q[(size_t)d * DD + lane + 32];
    float q2 = Q[(size_t)d * DD + lane + 64];
    float p0 = Qk[(size_t)d * DD + lane];
    float p1 = Qk[(size_t)d * DD + lane + 32];
    float p2 = Qk[(size_t)d * DD + lane + 64];
    int cnt = deg[d]; if (cnt > MAXDEG) cnt = MAXDEG;
    for (int c = 0; c < cnt; c++) {
        int2 se = pe[(size_t)d * MAXDEG + c];
        const float* kr = Kn + (size_t)se.x * DD;
        const float* er = ea + (size_t)se.y * DD;
        float dot = q0 * kr[lane] + q1 * kr[lane + 32] + q2 * kr[lane + 64]
                  + p0 * er[lane] + p1 * er[lane + 32] + p2 * er[lane + 64];
        dot = g32sum(dot);
        if (lane == 0) {
            float v = __expf(dot * scale);
            ae_slot[(size_t)d * MAXDEG + c] = v;
            atomicAdd(&denom[se.x], v);
        }
    }
}

__global__ __launch_bounds__(256)
void recip_k(float* __restrict__ d)
{
    int i = blockIdx.x * 256 + threadIdx.x;
    if (i < N_NODES) d[i] = 1.f / d[i];
}

// ---------------- edge pass 2 (gather): agg[d]=Σw·V[s]; T[d]=Σw·ea[e] ----------------
__global__ __launch_bounds__(256)
void edge2c(const float* __restrict__ V, const float* __restrict__ ea,
            const float* __restrict__ ae_slot, const float* __restrict__ dinv,
            const int2* __restrict__ pe, const int* __restrict__ deg,
            float* __restrict__ agg, float* __restrict__ T)
{
    int grp = threadIdx.x >> 5, lane = threadIdx.x & 31;
    int d = blockIdx.x * 8 + grp;
    if (d >= N_NODES) return;
    int cnt = deg[d]; if (cnt > MAXDEG) cnt = MAXDEG;
    float a0 = 0.f, a1 = 0.f, a2 = 0.f, t0 = 0.f, t1 = 0.f, t2 = 0.f;
    for (int c = 0; c < cnt; c++) {
        int2 se = pe[(size_t)d * MAXDEG + c];
        float w = ae_slot[(size_t)d * MAXDEG + c] * dinv[se.x];
        const float* vr = V + (size_t)se.x * DD;
        const float* er = ea + (size_t)se.y * DD;
        a0 += w * vr[lane];      a1 += w * vr[lane + 32]; a2 += w * vr[lane + 64];
        t0 += w * er[lane];      t1 += w * er[lane + 32]; t2 += w * er[lane + 64];
    }
    agg[(size_t)d * DD + lane] = a0;
    agg[(size_t)d * DD + lane + 32] = a1;
    agg[(size_t)d * DD + lane + 64] = a2;
    T[(size_t)d * DD + lane] = t0;
    T[(size_t)d * DD + lane + 32] = t1;
    T[(size_t)d * DD + lane + 64] = t2;
}

// ---------------- LayerNorm ----------------
template<int RL>
__global__ __launch_bounds__(256)
void ln_k(const float* __restrict__ a, const float* __restrict__ b,
          const float* __restrict__ g, const float* __restrict__ beta,
          float* __restrict__ out, int M)
{
    int wave = threadIdx.x >> 6;
    int lane = threadIdx.x & 63;
    int row = blockIdx.x * 4 + wave;
    if (row >= M) return;
    const int NE = (RL + 63) / 64;
    float vals[NE];
    float s = 0.f;
    #pragma unroll
    for (int i = 0; i < NE; i++) {
        int j = lane + i * 64;
        float x = 0.f;
        if (j < RL) {
            x = a[(size_t)row * RL + j];
            if (b) x += b[(size_t)row * RL + j];
        }
        vals[i] = x; s += x;
    }
    s = wave_reduce_sum(s);
    float mean = s / RL;
    float sq = 0.f;
    #pragma unroll
    for (int i = 0; i < NE; i++) {
        int j = lane + i * 64;
        if (j < RL) { float dd = vals[i] - mean; sq += dd * dd; }
    }
    sq = wave_reduce_sum(sq);
    float rstd = rsqrtf(sq / RL + 1e-5f);
    #pragma unroll
    for (int i = 0; i < NE; i++) {
        int j = lane + i * 64;
        if (j < RL) out[(size_t)row * RL + j] = (vals[i] - mean) * rstd * g[j] + beta[j];
    }
}

// ---------------- mean-pool scatter ----------------
__global__ __launch_bounds__(256)
void pool_k(const float* __restrict__ u, const int* __restrict__ batch,
            float* __restrict__ pooled, float* __restrict__ cnt)
{
    int n = blockIdx.x * 4 + (threadIdx.x >> 6);
    int lane = threadIdx.x & 63;
    if (n >= N_NODES) return;
    int bg = batch[n];
    #pragma unroll
    for (int i = 0; i < 6; i++) {
        int j = lane + i * 64;
        atomicAdd(&pooled[(size_t)bg * HH + j], u[(size_t)n * HH + j]);
    }
    if (lane == 0) atomicAdd(&cnt[bg], 1.f);
}

// ---------------- classifier head ----------------
__global__ __launch_bounds__(64)
void clf_k(const float* __restrict__ pooled, const float* __restrict__ cnt,
           const float* __restrict__ W, const float* __restrict__ bcl,
           float* __restrict__ out)
{
    int g = blockIdx.x;
    int lane = threadIdx.x;
    float c = cnt[g]; c = c > 1.f ? c : 1.f;
    float inv = 1.f / c;
    float a0 = 0.f, a1 = 0.f;
    #pragma unroll
    for (int i = 0; i < 6; i++) {
        int j = lane + i * 64;
        float pv = pooled[(size_t)g * HH + j] * inv;
        a0 += pv * W[j * 2 + 0];
        a1 += pv * W[j * 2 + 1];
    }
    a0 = wave_reduce_sum(a0);
    a1 = wave_reduce_sum(a1);
    if (lane == 0) {
        out[g * 2 + 0] = a0 + bcl[0];
        out[g * 2 + 1] = a1 + bcl[1];
    }
}

extern "C" void kernel_launch(void* const* d_in, const int* in_sizes, int n_in,
                              void* d_out, int out_size, void* d_ws, size_t ws_size,
                              hipStream_t stream)
{
    const float* x       = (const float*)d_in[0];
    const float* ea      = (const float*)d_in[1];
    const float* emb_W1  = (const float*)d_in[2];
    const float* emb_b1  = (const float*)d_in[3];
    const float* emb_W2  = (const float*)d_in[4];
    const float* emb_b2  = (const float*)d_in[5];
    const float* Wq      = (const float*)d_in[6];
    const float* Wk      = (const float*)d_in[7];
    const float* Wv      = (const float*)d_in[8];
    const float* ffn_W1  = (const float*)d_in[9];
    const float* ffn_W2  = (const float*)d_in[10];
    const float* bq      = (const float*)d_in[11];
    const float* bk      = (const float*)d_in[12];
    const float* bv      = (const float*)d_in[13];
    const float* ffn_b1  = (const float*)d_in[14];
    const float* ffn_b2  = (const float*)d_in[15];
    const float* n1_b    = (const float*)d_in[16];
    const float* n2_b    = (const float*)d_in[17];
    const float* n1_g    = (const float*)d_in[18];
    const float* n2_g    = (const float*)d_in[19];
    const float* u_W1    = (const float*)d_in[20];
    const float* u_b1    = (const float*)d_in[21];
    const float* u_W2    = (const float*)d_in[22];
    const float* u_b2    = (const float*)d_in[23];
    const float* u_g     = (const float*)d_in[24];
    const float* u_bb    = (const float*)d_in[25];
    const float* clf_W   = (const float*)d_in[26];
    const float* clf_b   = (const float*)d_in[27];
    const float* rec_W1  = (const float*)d_in[28];
    const float* rec_b1  = (const float*)d_in[29];
    const float* rec_W2  = (const float*)d_in[30];
    const float* rec_b2  = (const float*)d_in[31];
    const int* edge_index = (const int*)d_in[32];
    const int* batch     = (const int*)d_in[33];
    const int* srcI = edge_index;
    const int* dstI = edge_index + N_EDGES;

    float* out   = (float*)d_out;
    float* r_out = out + NGRAPH * NOUT_;

    // workspace carve-up (~174 MB)
    float* p = (float*)d_ws;
    float* h      = p; p += (size_t)N_NODES * DD;
    float* bufH1  = p; p += (size_t)N_NODES * HH;
    float* bufH2  = p; p += (size_t)N_NODES * HH;
    float* denom  = p; p += N_NODES;
    float* pooled = p; p += NGRAPH * HH;
    float* cnt    = p; p += NGRAPH;
    int*   deg    = (int*)p; p += N_NODES;
    // adjacency aliased into bufH1 (bufH1 unused during the 4 layers)
    int2*  pe      = (int2*)bufH1;                                  // 25.6 MB
    float* ae_slot = bufH1 + (size_t)N_NODES * MAXDEG * 2;          // 12.8 MB

    dim3 blk(256);
    const int GB = (N_NODES + 127) / 128;   // 391
    const float scale = 1.f / sqrtf((float)DD);

    // ---- atom embedding MLP (uses bufH1, before adjacency aliasing) ----
    gemm2<128,128,16,8,8,ACT_RELU,false,false><<<dim3(GB,3), blk, 0, stream>>>(
        x, emb_W1, emb_b1, bufH1, N_NODES, HH, INF_);
    gemm2<128,96,16,8,6,ACT_NONE,false,false><<<dim3(GB,1), blk, 0, stream>>>(
        bufH1, emb_W2, emb_b2, h, N_NODES, DD, HH);

    // ---- adjacency build (once; reused all 4 layers) ----
    hipMemsetAsync(deg, 0, N_NODES * sizeof(int), stream);
    scatter_k<<<(N_EDGES + 255) / 256, blk, 0, stream>>>(srcI, dstI, deg, pe);

    // ---- RPETConv layers ----
    for (int l = 0; l < NLAYERS; l++) {
        const float* Wq_l = Wq + (size_t)l * DD * DD;
        const float* Wk_l = Wk + (size_t)l * DD * DD;
        const float* Wv_l = Wv + (size_t)l * DD * DD;
        const float* W1_l = ffn_W1 + (size_t)l * DD * DD;
        const float* W2_l = ffn_W2 + (size_t)l * DD * DD;

        float* Qb  = bufH2;
        float* Kb  = bufH2 + (size_t)N_NODES * DD;
        float* Vb  = bufH2 + 2 * (size_t)N_NODES * DD;
        float* Qkb = bufH2 + 3 * (size_t)N_NODES * DD;

        gemm2<128,96,16,8,6,ACT_NONE,false,false><<<dim3(GB,1), blk, 0, stream>>>(
            h, Wq_l, bq + (size_t)l * DD, Qb, N_NODES, DD, DD);
        gemm2<128,96,16,8,6,ACT_NONE,false,false><<<dim3(GB,1), blk, 0, stream>>>(
            h, Wk_l, bk + (size_t)l * DD, Kb, N_NODES, DD, DD);
        gemm2<128,96,16,8,6,ACT_NONE,false,false><<<dim3(GB,1), blk, 0, stream>>>(
            h, Wv_l, bv + (size_t)l * DD, Vb, N_NODES, DD, DD);
        gemm2<128,96,16,8,6,ACT_NONE,true,false><<<dim3(GB,1), blk, 0, stream>>>(
            Qb, Wk_l, nullptr, Qkb, N_NODES, DD, DD);

        hipMemsetAsync(denom, 0, N_NODES * sizeof(float), stream);
        edge1c<<<(N_NODES + 7) / 8, blk, 0, stream>>>(
            Qb, Kb, Qkb, ea, pe, deg, ae_slot, denom, scale);
        recip_k<<<(N_NODES + 255) / 256, blk, 0, stream>>>(denom);

        float* agg = Qb;   // Q dead after pass 1
        float* T   = Kb;   // K dead after pass 1
        edge2c<<<(N_NODES + 7) / 8, blk, 0, stream>>>(
            Vb, ea, ae_slot, denom, pe, deg, agg, T);

        // agg += T @ Wv
        gemm2<128,96,16,8,6,ACT_NONE,false,true><<<dim3(GB,1), blk, 0, stream>>>(
            T, Wv_l, nullptr, agg, N_NODES, DD, DD);

        float* h1 = Qkb;   // Qk dead
        ln_k<DD><<<(N_NODES + 3) / 4, blk, 0, stream>>>(
            h, agg, n1_g + (size_t)l * DD, n1_b + (size_t)l * DD, h1, N_NODES);

        gemm2<128,96,16,8,6,ACT_ELU,false,false><<<dim3(GB,1), blk, 0, stream>>>(
            h1, W1_l, ffn_b1 + (size_t)l * DD, Vb, N_NODES, DD, DD);
        gemm2<128,96,16,8,6,ACT_NONE,false,false><<<dim3(GB,1), blk, 0, stream>>>(
            Vb, W2_l, ffn_b2 + (size_t)l * DD, agg, N_NODES, DD, DD);
        ln_k<DD><<<(N_NODES + 3) / 4, blk, 0, stream>>>(
            agg, h1, n2_g + (size_t)l * DD, n2_b + (size_t)l * DD, h, N_NODES);
    }

    // ---- updim + LN ----
    gemm2<128,128,16,8,8,ACT_LEAKY,false,false><<<dim3(GB,3), blk, 0, stream>>>(
        h, u_W1, u_b1, bufH2, N_NODES, HH, DD);
    gemm2<128,128,16,8,8,ACT_NONE,false,false><<<dim3(GB,3), blk, 0, stream>>>(
        bufH2, u_W2, u_b2, bufH1, N_NODES, HH, HH);
    ln_k<HH><<<(N_NODES + 3) / 4, blk, 0, stream>>>(
        bufH1, nullptr, u_g, u_bb, bufH1, N_NODES);

    // ---- mean pool + classifier ----
    hipMemsetAsync(pooled, 0, (size_t)(NGRAPH * HH + NGRAPH) * sizeof(float), stream);
    pool_k<<<(N_NODES + 3) / 4, blk, 0, stream>>>(bufH1, batch, pooled, cnt);
    clf_k<<<NGRAPH, 64, 0, stream>>>(pooled, cnt, clf_W, clf_b, out);

    // ---- reconstruction head ----
    gemm2<128,128,16,8,8,ACT_RELU,false,false><<<dim3(GB,3), blk, 0, stream>>>(
        bufH1, rec_W1, rec_b1, bufH2, N_NODES, HH, HH);
    gemm2<128,64,16,8,4,ACT_NONE,false,false><<<dim3(GB,1), blk, 0, stream>>>(
        bufH2, rec_W2, rec_b2, r_out, N_NODES, INF_, HH);
}

// Round 3
// 2960.619 us; speedup vs baseline: 1.5392x; 1.0591x over previous
//
#include <hip/hip_runtime.h>
#include <math.h>

#define N_NODES 50000
#define N_EDGES 640000
#define INF_ 64
#define DD 96
#define HH 384
#define NLAYERS 4
#define NGRAPH 512
#define NOUT_ 2
#define MAXDEG 64

#define ACT_NONE 0
#define ACT_RELU 1
#define ACT_ELU 2
#define ACT_LEAKY 3

typedef unsigned int uint;
typedef unsigned short ushort;

__device__ __forceinline__ float bf_lo(uint u) { return __uint_as_float(u << 16); }
__device__ __forceinline__ float bf_hi(uint u) { return __uint_as_float(u & 0xffff0000u); }
__device__ __forceinline__ float bfs(ushort s) { return __uint_as_float(((uint)s) << 16); }
__device__ __forceinline__ ushort f2bf(float f)
{
    uint u = __float_as_uint(f);
    return (ushort)((u + 0x7fffu + ((u >> 16) & 1u)) >> 16);
}

// ---------------- fp32 tiled GEMM v3: C = act(A@B (+bias) (+C)), optional bf16 out ----------
// A: M x K row-major. B: K x Nc row-major. 256 thr, BM=128, TX=16, TY=16, TM=8.
// TN==8 -> BN=128 (cols tx*4+j | BN/2+tx*4+j-4); TN==6 -> BN=96; TN==4 -> BN=64.
template<int BN, int TN, int ACT, bool ACCUM, bool BF16OUT>
__global__ __launch_bounds__(256)
void gemm3(const float* __restrict__ A, const float* __restrict__ B,
           const float* __restrict__ bias, float* __restrict__ C,
           ushort* __restrict__ C16, int M, int Nc, int K)
{
    const int BM = 128, BK = 16, TM = 8;
    __shared__ float As[BK][BM + 4];
    __shared__ float Bs[BK][BN + 4];
    int tid = threadIdx.x;
    int tx = tid & 15, ty = tid >> 4;
    int bm0 = blockIdx.x * BM, bn0 = blockIdx.y * BN;
    float acc[TM][TN] = {};
    for (int k0 = 0; k0 < K; k0 += BK) {
        #pragma unroll
        for (int it = 0; it < 2; it++) {
            int idx = it * 256 + tid;   // 512 float4 slots
            int m = idx >> 2;
            int kk = (idx & 3) * 4;
            int row = bm0 + m;
            float4 v = make_float4(0.f, 0.f, 0.f, 0.f);
            if (row < M) v = *(const float4*)&A[(size_t)row * K + k0 + kk];
            As[kk + 0][m] = v.x; As[kk + 1][m] = v.y;
            As[kk + 2][m] = v.z; As[kk + 3][m] = v.w;
        }
        for (int idx = tid; idx < BK * BN / 4; idx += 256) {
            int kk = idx / (BN / 4);
            int nn = (idx % (BN / 4)) * 4;
            *(float4*)&Bs[kk][nn] = *(const float4*)&B[(size_t)(k0 + kk) * Nc + bn0 + nn];
        }
        __syncthreads();
        #pragma unroll
        for (int k = 0; k < BK; k++) {
            float4 a0 = *(const float4*)&As[k][ty * 8];
            float4 a1 = *(const float4*)&As[k][ty * 8 + 4];
            float a[TM] = {a0.x, a0.y, a0.z, a0.w, a1.x, a1.y, a1.z, a1.w};
            float b[TN];
            if (TN == 8) {
                float4 b0 = *(const float4*)&Bs[k][tx * 4];
                float4 b1 = *(const float4*)&Bs[k][BN / 2 + tx * 4];
                b[0] = b0.x; b[1] = b0.y; b[2] = b0.z; b[3] = b0.w;
                b[4] = b1.x; b[5] = b1.y; b[6] = b1.z; b[7] = b1.w;
            } else if (TN == 6) {
                float2 b0 = *(const float2*)&Bs[k][tx * 2];
                float2 b1 = *(const float2*)&Bs[k][32 + tx * 2];
                float2 b2 = *(const float2*)&Bs[k][64 + tx * 2];
                b[0] = b0.x; b[1] = b0.y; b[2] = b1.x; b[3] = b1.y; b[4] = b2.x; b[5] = b2.y;
            } else {
                float4 b0 = *(const float4*)&Bs[k][tx * 4];
                b[0] = b0.x; b[1] = b0.y; b[2] = b0.z; b[3] = b0.w;
            }
            #pragma unroll
            for (int i = 0; i < TM; i++)
                #pragma unroll
                for (int j = 0; j < TN; j++)
                    acc[i][j] += a[i] * b[j];
        }
        __syncthreads();
    }
    #pragma unroll
    for (int i = 0; i < TM; i++) {
        int row = bm0 + ty * 8 + i;
        if (row >= M) continue;
        #pragma unroll
        for (int j = 0; j < TN; j++) {
            int col;
            if (TN == 8)      col = bn0 + ((j < 4) ? tx * 4 + j : BN / 2 + tx * 4 + j - 4);
            else if (TN == 6) col = bn0 + (j >> 1) * 32 + tx * 2 + (j & 1);
            else              col = bn0 + tx * 4 + j;
            float v = acc[i][j];
            if (bias) v += bias[col];
            if (ACCUM) v += C[(size_t)row * Nc + col];
            if (ACT == ACT_RELU)       v = fmaxf(v, 0.f);
            else if (ACT == ACT_ELU)   v = v > 0.f ? v : expm1f(v);
            else if (ACT == ACT_LEAKY) v = v > 0.f ? v : 0.01f * v;
            if (BF16OUT) C16[(size_t)row * Nc + col] = f2bf(v);
            else         C[(size_t)row * Nc + col] = v;
        }
    }
}

__device__ __forceinline__ float wave_reduce_sum(float v)
{
    #pragma unroll
    for (int o = 32; o > 0; o >>= 1) v += __shfl_xor(v, o, 64);
    return v;
}

__device__ __forceinline__ float g32sum(float v)
{
    #pragma unroll
    for (int o = 16; o > 0; o >>= 1) v += __shfl_xor(v, o, 64);
    return v;
}

// ---------------- precompute Wqk = Wq@Wk^T, bqk = bq@Wk^T -> packed cols 288..383 ----------
__global__ __launch_bounds__(256)
void wqk_k(const float* __restrict__ Wq, const float* __restrict__ Wk,
           const float* __restrict__ bq, float* __restrict__ Wcat, float* __restrict__ bcat)
{
    int l = blockIdx.y;
    int idx = blockIdx.x * 256 + threadIdx.x;
    const float* wq = Wq + (size_t)l * DD * DD;
    const float* wk = Wk + (size_t)l * DD * DD;
    if (idx < DD * DD) {
        int k = idx / DD, j = idx % DD;
        float s = 0.f;
        for (int t = 0; t < DD; t++) s += wq[k * DD + t] * wk[j * DD + t];
        Wcat[(size_t)l * DD * 4 * DD + (size_t)k * 4 * DD + 288 + j] = s;
    }
    if (idx < DD) {
        int j = idx;
        float s = 0.f;
        for (int t = 0; t < DD; t++) s += bq[l * DD + t] * wk[j * DD + t];
        bcat[l * 4 * DD + 288 + j] = s;
    }
}

// ---------------- pack [Wq|Wk|Wv] cols 0..287 + biases ----------------
__global__ __launch_bounds__(256)
void pack_k(const float* __restrict__ Wq, const float* __restrict__ Wk,
            const float* __restrict__ Wv, const float* __restrict__ bq,
            const float* __restrict__ bk, const float* __restrict__ bv,
            float* __restrict__ Wcat, float* __restrict__ bcat)
{
    int idx = blockIdx.x * 256 + threadIdx.x;          // over 4*96*288
    if (idx >= NLAYERS * DD * 288) return;
    int l = idx / (DD * 288);
    int rem = idx % (DD * 288);
    int k = rem / 288, n = rem % 288;
    int which = n / DD, j = n % DD;
    const float* W = which == 0 ? Wq : (which == 1 ? Wk : Wv);
    Wcat[(size_t)l * DD * 4 * DD + (size_t)k * 4 * DD + n] =
        W[(size_t)l * DD * DD + k * DD + j];
    if (k == 0) {
        const float* bb = which == 0 ? bq : (which == 1 ? bk : bv);
        bcat[l * 4 * DD + n] = bb[l * DD + j];
    }
}

// ---------------- adjacency build (padded slots) ----------------
__global__ __launch_bounds__(256)
void scatter_k(const int* __restrict__ src, const int* __restrict__ dst,
               int* __restrict__ deg, int2* __restrict__ pe)
{
    int e = blockIdx.x * 256 + threadIdx.x;
    if (e >= N_EDGES) return;
    int d = dst[e];
    int c = atomicAdd(&deg[d], 1);
    if (c < MAXDEG) pe[(size_t)d * MAXDEG + c] = make_int2(src[e], e);
}

// ---------------- edge pass 1: ae=exp(scale*(Q[d]·K[s] + Qk[d]·ea[e])), denom[s]+=ae -------
// qkv16 row layout (bf16, stride 384): [0:96]=Q [96:192]=K [192:288]=V [288:384]=Qk
__global__ __launch_bounds__(256)
void edge1b(const ushort* __restrict__ qkv16, const float* __restrict__ ea,
            const int2* __restrict__ pe, const int* __restrict__ deg,
            float* __restrict__ ae_slot, float* __restrict__ denom, float scale)
{
    int grp = threadIdx.x >> 5, lane = threadIdx.x & 31;
    int d = blockIdx.x * 8 + grp;
    if (d >= N_NODES) return;
    const uint* qrow = (const uint*)(qkv16 + (size_t)d * 384);
    uint qu0 = qrow[lane];
    uint qu1 = (lane < 16) ? qrow[32 + lane] : 0u;
    float q00 = bf_lo(qu0), q01 = bf_hi(qu0);
    float q10 = bf_lo(qu1), q11 = bf_hi(qu1);
    const ushort* prow = qkv16 + (size_t)d * 384 + 288;
    float p0 = bfs(prow[lane]), p1 = bfs(prow[lane + 32]), p2 = bfs(prow[lane + 64]);
    int2 pr0 = pe[(size_t)d * MAXDEG + lane];
    int2 pr1 = pe[(size_t)d * MAXDEG + 32 + lane];
    int cnt = deg[d]; if (cnt > MAXDEG) cnt = MAXDEG;
    for (int c = 0; c < cnt; c++) {
        int sx = __shfl(c < 32 ? pr0.x : pr1.x, c & 31, 32);
        int ex = __shfl(c < 32 ? pr0.y : pr1.y, c & 31, 32);
        const uint* krow = (const uint*)(qkv16 + (size_t)sx * 384 + 96);
        const float* erow = ea + (size_t)ex * DD;
        uint ku0 = krow[lane];
        float e0 = erow[lane], e1 = erow[lane + 32], e2 = erow[lane + 64];
        float dot = q00 * bf_lo(ku0) + q01 * bf_hi(ku0) + p0 * e0 + p1 * e1 + p2 * e2;
        if (lane < 16) {
            uint ku1 = krow[32 + lane];
            dot += q10 * bf_lo(ku1) + q11 * bf_hi(ku1);
        }
        dot = g32sum(dot);
        if (lane == 0) {
            float v = __expf(dot * scale);
            ae_slot[(size_t)d * MAXDEG + c] = v;
            atomicAdd(&denom[sx], v);
        }
    }
}

__global__ __launch_bounds__(256)
void recip_k(float* __restrict__ d)
{
    int i = blockIdx.x * 256 + threadIdx.x;
    if (i < N_NODES) d[i] = 1.f / d[i];
}

// ---------------- edge pass 2: agg[d]=Σw·V[s]; T[d]=Σw·ea[e] ----------------
__global__ __launch_bounds__(256)
void edge2b(const ushort* __restrict__ qkv16, const float* __restrict__ ea,
            const float* __restrict__ ae_slot, const float* __restrict__ dinv,
            const int2* __restrict__ pe, const int* __restrict__ deg,
            float* __restrict__ agg, float* __restrict__ T)
{
    int grp = threadIdx.x >> 5, lane = threadIdx.x & 31;
    int d = blockIdx.x * 8 + grp;
    if (d >= N_NODES) return;
    int2 pr0 = pe[(size_t)d * MAXDEG + lane];
    int2 pr1 = pe[(size_t)d * MAXDEG + 32 + lane];
    float ar0 = ae_slot[(size_t)d * MAXDEG + lane];
    float ar1 = ae_slot[(size_t)d * MAXDEG + 32 + lane];
    int cnt = deg[d]; if (cnt > MAXDEG) cnt = MAXDEG;
    float a00 = 0.f, a01 = 0.f, a10 = 0.f, a11 = 0.f;
    float t0 = 0.f, t1 = 0.f, t2 = 0.f;
    for (int c = 0; c < cnt; c++) {
        int sx = __shfl(c < 32 ? pr0.x : pr1.x, c & 31, 32);
        int ex = __shfl(c < 32 ? pr0.y : pr1.y, c & 31, 32);
        float ae = __shfl(c < 32 ? ar0 : ar1, c & 31, 32);
        float w = ae * dinv[sx];
        const uint* vrow = (const uint*)(qkv16 + (size_t)sx * 384 + 192);
        const float* erow = ea + (size_t)ex * DD;
        uint vu0 = vrow[lane];
        a00 += w * bf_lo(vu0); a01 += w * bf_hi(vu0);
        if (lane < 16) {
            uint vu1 = vrow[32 + lane];
            a10 += w * bf_lo(vu1); a11 += w * bf_hi(vu1);
        }
        t0 += w * erow[lane];
        t1 += w * erow[lane + 32];
        t2 += w * erow[lane + 64];
    }
    *(float2*)&agg[(size_t)d * DD + 2 * lane] = make_float2(a00, a01);
    if (lane < 16)
        *(float2*)&agg[(size_t)d * DD + 64 + 2 * lane] = make_float2(a10, a11);
    T[(size_t)d * DD + lane] = t0;
    T[(size_t)d * DD + lane + 32] = t1;
    T[(size_t)d * DD + lane + 64] = t2;
}

// ---------------- LayerNorm ----------------
template<int RL>
__global__ __launch_bounds__(256)
void ln_k(const float* __restrict__ a, const float* __restrict__ b,
          const float* __restrict__ g, const float* __restrict__ beta,
          float* __restrict__ out, int M)
{
    int wave = threadIdx.x >> 6;
    int lane = threadIdx.x & 63;
    int row = blockIdx.x * 4 + wave;
    if (row >= M) return;
    const int NE = (RL + 63) / 64;
    float vals[NE];
    float s = 0.f;
    #pragma unroll
    for (int i = 0; i < NE; i++) {
        int j = lane + i * 64;
        float x = 0.f;
        if (j < RL) {
            x = a[(size_t)row * RL + j];
            if (b) x += b[(size_t)row * RL + j];
        }
        vals[i] = x; s += x;
    }
    s = wave_reduce_sum(s);
    float mean = s / RL;
    float sq = 0.f;
    #pragma unroll
    for (int i = 0; i < NE; i++) {
        int j = lane + i * 64;
        if (j < RL) { float dd = vals[i] - mean; sq += dd * dd; }
    }
    sq = wave_reduce_sum(sq);
    float rstd = rsqrtf(sq / RL + 1e-5f);
    #pragma unroll
    for (int i = 0; i < NE; i++) {
        int j = lane + i * 64;
        if (j < RL) out[(size_t)row * RL + j] = (vals[i] - mean) * rstd * g[j] + beta[j];
    }
}

// ---------------- mean-pool scatter ----------------
__global__ __launch_bounds__(256)
void pool_k(const float* __restrict__ u, const int* __restrict__ batch,
            float* __restrict__ pooled, float* __restrict__ cnt)
{
    int n = blockIdx.x * 4 + (threadIdx.x >> 6);
    int lane = threadIdx.x & 63;
    if (n >= N_NODES) return;
    int bg = batch[n];
    #pragma unroll
    for (int i = 0; i < 6; i++) {
        int j = lane + i * 64;
        atomicAdd(&pooled[(size_t)bg * HH + j], u[(size_t)n * HH + j]);
    }
    if (lane == 0) atomicAdd(&cnt[bg], 1.f);
}

// ---------------- classifier head ----------------
__global__ __launch_bounds__(64)
void clf_k(const float* __restrict__ pooled, const float* __restrict__ cnt,
           const float* __restrict__ W, const float* __restrict__ bcl,
           float* __restrict__ out)
{
    int g = blockIdx.x;
    int lane = threadIdx.x;
    float c = cnt[g]; c = c > 1.f ? c : 1.f;
    float inv = 1.f / c;
    float a0 = 0.f, a1 = 0.f;
    #pragma unroll
    for (int i = 0; i < 6; i++) {
        int j = lane + i * 64;
        float pv = pooled[(size_t)g * HH + j] * inv;
        a0 += pv * W[j * 2 + 0];
        a1 += pv * W[j * 2 + 1];
    }
    a0 = wave_reduce_sum(a0);
    a1 = wave_reduce_sum(a1);
    if (lane == 0) {
        out[g * 2 + 0] = a0 + bcl[0];
        out[g * 2 + 1] = a1 + bcl[1];
    }
}

extern "C" void kernel_launch(void* const* d_in, const int* in_sizes, int n_in,
                              void* d_out, int out_size, void* d_ws, size_t ws_size,
                              hipStream_t stream)
{
    const float* x       = (const float*)d_in[0];
    const float* ea      = (const float*)d_in[1];
    const float* emb_W1  = (const float*)d_in[2];
    const float* emb_b1  = (const float*)d_in[3];
    const float* emb_W2  = (const float*)d_in[4];
    const float* emb_b2  = (const float*)d_in[5];
    const float* Wq      = (const float*)d_in[6];
    const float* Wk      = (const float*)d_in[7];
    const float* Wv      = (const float*)d_in[8];
    const float* ffn_W1  = (const float*)d_in[9];
    const float* ffn_W2  = (const float*)d_in[10];
    const float* bq      = (const float*)d_in[11];
    const float* bk      = (const float*)d_in[12];
    const float* bv      = (const float*)d_in[13];
    const float* ffn_b1  = (const float*)d_in[14];
    const float* ffn_b2  = (const float*)d_in[15];
    const float* n1_b    = (const float*)d_in[16];
    const float* n2_b    = (const float*)d_in[17];
    const float* n1_g    = (const float*)d_in[18];
    const float* n2_g    = (const float*)d_in[19];
    const float* u_W1    = (const float*)d_in[20];
    const float* u_b1    = (const float*)d_in[21];
    const float* u_W2    = (const float*)d_in[22];
    const float* u_b2    = (const float*)d_in[23];
    const float* u_g     = (const float*)d_in[24];
    const float* u_bb    = (const float*)d_in[25];
    const float* clf_W   = (const float*)d_in[26];
    const float* clf_b   = (const float*)d_in[27];
    const float* rec_W1  = (const float*)d_in[28];
    const float* rec_b1  = (const float*)d_in[29];
    const float* rec_W2  = (const float*)d_in[30];
    const float* rec_b2  = (const float*)d_in[31];
    const int* edge_index = (const int*)d_in[32];
    const int* batch     = (const int*)d_in[33];
    const int* srcI = edge_index;
    const int* dstI = edge_index + N_EDGES;

    float* out   = (float*)d_out;
    float* r_out = out + NGRAPH * NOUT_;

    // ---- workspace carve-up (~175 MB, same footprint as R2) ----
    float* p = (float*)d_ws;
    float* h       = p; p += (size_t)N_NODES * DD;       // 19.2 MB
    float* region1 = p; p += (size_t)N_NODES * HH;       // 76.8 MB
    float* region2 = p; p += (size_t)N_NODES * HH;       // 76.8 MB
    float* denom   = p; p += N_NODES;
    float* pooled  = p; p += NGRAPH * HH;
    float* cnt     = p; p += NGRAPH;
    int*   deg     = (int*)p; p += N_NODES;
    float* Wcat    = p; p += (size_t)NLAYERS * DD * 4 * DD;   // 0.59 MB
    float* bcat    = p; p += NLAYERS * 4 * DD;

    // layer-phase aliases
    ushort* qkv16 = (ushort*)region1;                          // N*384 bf16 = N*192 fl
    float*  agg   = region1 + (size_t)N_NODES * 192;
    float*  T     = agg + (size_t)N_NODES * DD;
    float*  h1    = region2;
    int2*   pe    = (int2*)(region2 + (size_t)N_NODES * DD);   // N*64 int2 = N*128 fl
    float*  ae_slot = region2 + (size_t)N_NODES * (DD + 128);  // N*64 fl
    // head-phase aliases
    float* tmp1 = region1;    // N x 384
    float* u    = region2;    // N x 384
    float* rtmp = region1;    // N x 384

    dim3 blk(256);
    const int GB = (N_NODES + 127) / 128;   // 391
    const float scale = 1.f / sqrtf((float)DD);

    // ---- weight precompute/pack ----
    wqk_k<<<dim3(36, NLAYERS), blk, 0, stream>>>(Wq, Wk, bq, Wcat, bcat);
    pack_k<<<(NLAYERS * DD * 288 + 255) / 256, blk, 0, stream>>>(
        Wq, Wk, Wv, bq, bk, bv, Wcat, bcat);

    // ---- atom embedding MLP (region1 free until qkv16) ----
    gemm3<128, 8, ACT_RELU, false, false><<<dim3(GB, 3), blk, 0, stream>>>(
        x, emb_W1, emb_b1, region1, nullptr, N_NODES, HH, INF_);
    gemm3<96, 6, ACT_NONE, false, false><<<dim3(GB, 1), blk, 0, stream>>>(
        region1, emb_W2, emb_b2, h, nullptr, N_NODES, DD, HH);

    // ---- adjacency build ----
    hipMemsetAsync(deg, 0, N_NODES * sizeof(int), stream);
    scatter_k<<<(N_EDGES + 255) / 256, blk, 0, stream>>>(srcI, dstI, deg, pe);

    // ---- RPETConv layers ----
    for (int l = 0; l < NLAYERS; l++) {
        const float* W1_l = ffn_W1 + (size_t)l * DD * DD;
        const float* W2_l = ffn_W2 + (size_t)l * DD * DD;

        // fused QKVQk: bf16 out, N x 384
        gemm3<128, 8, ACT_NONE, false, true><<<dim3(GB, 3), blk, 0, stream>>>(
            h, Wcat + (size_t)l * DD * 4 * DD, bcat + (size_t)l * 4 * DD,
            nullptr, qkv16, N_NODES, 4 * DD, DD);

        hipMemsetAsync(denom, 0, N_NODES * sizeof(float), stream);
        edge1b<<<(N_NODES + 7) / 8, blk, 0, stream>>>(
            qkv16, ea, pe, deg, ae_slot, denom, scale);
        recip_k<<<(N_NODES + 255) / 256, blk, 0, stream>>>(denom);
        edge2b<<<(N_NODES + 7) / 8, blk, 0, stream>>>(
            qkv16, ea, ae_slot, denom, pe, deg, agg, T);

        // agg += T @ Wv
        gemm3<96, 6, ACT_NONE, true, false><<<dim3(GB, 1), blk, 0, stream>>>(
            T, Wv + (size_t)l * DD * DD, nullptr, agg, nullptr, N_NODES, DD, DD);

        ln_k<DD><<<(N_NODES + 3) / 4, blk, 0, stream>>>(
            h, agg, n1_g + (size_t)l * DD, n1_b + (size_t)l * DD, h1, N_NODES);

        float* f1 = T;  // T dead after Wv-accum
        gemm3<96, 6, ACT_ELU, false, false><<<dim3(GB, 1), blk, 0, stream>>>(
            h1, W1_l, ffn_b1 + (size_t)l * DD, f1, nullptr, N_NODES, DD, DD);
        gemm3<96, 6, ACT_NONE, false, false><<<dim3(GB, 1), blk, 0, stream>>>(
            f1, W2_l, ffn_b2 + (size_t)l * DD, agg, nullptr, N_NODES, DD, DD);
        ln_k<DD><<<(N_NODES + 3) / 4, blk, 0, stream>>>(
            agg, h1, n2_g + (size_t)l * DD, n2_b + (size_t)l * DD, h, N_NODES);
    }

    // ---- updim + LN ----
    gemm3<128, 8, ACT_LEAKY, false, false><<<dim3(GB, 3), blk, 0, stream>>>(
        h, u_W1, u_b1, tmp1, nullptr, N_NODES, HH, DD);
    gemm3<128, 8, ACT_NONE, false, false><<<dim3(GB, 3), blk, 0, stream>>>(
        tmp1, u_W2, u_b2, u, nullptr, N_NODES, HH, HH);
    ln_k<HH><<<(N_NODES + 3) / 4, blk, 0, stream>>>(
        u, nullptr, u_g, u_bb, u, N_NODES);

    // ---- mean pool + classifier ----
    hipMemsetAsync(pooled, 0, (size_t)(NGRAPH * HH + NGRAPH) * sizeof(float), stream);
    pool_k<<<(N_NODES + 3) / 4, blk, 0, stream>>>(u, batch, pooled, cnt);
    clf_k<<<NGRAPH, 64, 0, stream>>>(pooled, cnt, clf_W, clf_b, out);

    // ---- reconstruction head ----
    gemm3<128, 8, ACT_RELU, false, false><<<dim3(GB, 3), blk, 0, stream>>>(
        u, rec_W1, rec_b1, rtmp, nullptr, N_NODES, HH, HH);
    gemm3<64, 4, ACT_NONE, false, false><<<dim3(GB, 1), blk, 0, stream>>>(
        rtmp, rec_W2, rec_b2, r_out, nullptr, N_NODES, INF_, HH);
}

// Round 4
// 2037.567 us; speedup vs baseline: 2.2365x; 1.4530x over previous
//
#include <hip/hip_runtime.h>
#include <math.h>

#define N_NODES 50000
#define N_EDGES 640000
#define INF_ 64
#define DD 96
#define HH 384
#define NLAYERS 4
#define NGRAPH 512
#define NOUT_ 2
#define MAXDEG 64

#define ACT_NONE 0
#define ACT_RELU 1
#define ACT_ELU 2
#define ACT_LEAKY 3

typedef unsigned int uint;
typedef unsigned short ushort;
typedef __attribute__((ext_vector_type(8))) short v8s;   // 8 bf16 (4 VGPRs)
typedef __attribute__((ext_vector_type(4))) float v4f;   // 4 fp32 acc

__device__ __forceinline__ float bf_lo(uint u) { return __uint_as_float(u << 16); }
__device__ __forceinline__ float bf_hi(uint u) { return __uint_as_float(u & 0xffff0000u); }
__device__ __forceinline__ float bfs(ushort s) { return __uint_as_float(((uint)s) << 16); }
__device__ __forceinline__ ushort f2bf(float f)
{
    uint u = __float_as_uint(f);
    return (ushort)((u + 0x7fffu + ((u >> 16) & 1u)) >> 16);
}

// ================= MFMA bf16 GEMM: C = act(A@B (+bias) (+C)) =================
// A: M x K bf16 row-major. Bt: N x K bf16 row-major (pre-transposed weights).
// BM=128, 256 thr = 4 waves (2x2), wave tile 64 x BN/2. K % 32 == 0, Nc % BN == 0.
template<int BN, int ACT, bool ACCUM, bool OUT16>
__global__ __launch_bounds__(256)
void gemm_mf(const ushort* __restrict__ A, const ushort* __restrict__ Bt,
             const float* __restrict__ bias, float* __restrict__ C32,
             ushort* __restrict__ C16, int M, int Nc, int K)
{
    const int BM = 128, LDA = 40;      // 32 + 8 pad (bf16 units) -> 2-way b128, free
    const int FN = BN / 32;            // n-fragments per wave
    __shared__ ushort As[BM * LDA];
    __shared__ ushort Bs[BN * LDA];
    int tid = threadIdx.x;
    int lane = tid & 63, wave = tid >> 6;
    int ln15 = lane & 15, quad = lane >> 4;
    int wm = (wave >> 1) * 64, wn = (wave & 1) * (BN / 2);
    int bm0 = blockIdx.x * BM, bn0 = blockIdx.y * BN;

    v4f acc[4][FN];
    #pragma unroll
    for (int i = 0; i < 4; i++)
        #pragma unroll
        for (int j = 0; j < FN; j++) acc[i][j] = (v4f){0.f, 0.f, 0.f, 0.f};

    for (int k0 = 0; k0 < K; k0 += 32) {
        // stage A tile: 128 x 32 bf16, 16B units
        #pragma unroll
        for (int it = 0; it < 2; it++) {
            int u = it * 256 + tid;
            int r = u >> 2, c8 = (u & 3) * 8;
            int row = bm0 + r;
            int4 v = make_int4(0, 0, 0, 0);
            if (row < M) v = *(const int4*)&A[(size_t)row * K + k0 + c8];
            *(int4*)&As[r * LDA + c8] = v;
        }
        // stage Bt tile: BN x 32
        #pragma unroll
        for (int it = 0; it < (BN * 4 + 255) / 256; it++) {
            int u = it * 256 + tid;
            if ((BN * 4) % 256 == 0 || u < BN * 4) {
                int r = u >> 2, c8 = (u & 3) * 8;
                *(int4*)&Bs[r * LDA + c8] =
                    *(const int4*)&Bt[(size_t)(bn0 + r) * K + k0 + c8];
            }
        }
        __syncthreads();
        v8s af[4], bf[FN];
        #pragma unroll
        for (int i = 0; i < 4; i++)
            af[i] = *(const v8s*)&As[(wm + i * 16 + ln15) * LDA + quad * 8];
        #pragma unroll
        for (int j = 0; j < FN; j++)
            bf[j] = *(const v8s*)&Bs[(wn + j * 16 + ln15) * LDA + quad * 8];
        #pragma unroll
        for (int i = 0; i < 4; i++)
            #pragma unroll
            for (int j = 0; j < FN; j++)
                acc[i][j] = __builtin_amdgcn_mfma_f32_16x16x32_bf16(
                    af[i], bf[j], acc[i][j], 0, 0, 0);
        __syncthreads();
    }
    // epilogue: C/D layout col=lane&15, row=quad*4+reg
    #pragma unroll
    for (int i = 0; i < 4; i++) {
        #pragma unroll
        for (int j = 0; j < FN; j++) {
            int col = bn0 + wn + j * 16 + ln15;
            float bsv = bias ? bias[col] : 0.f;
            #pragma unroll
            for (int r = 0; r < 4; r++) {
                int row = bm0 + wm + i * 16 + quad * 4 + r;
                if (row >= M) continue;
                float v = acc[i][j][r] + bsv;
                if (ACCUM) v += C32[(size_t)row * Nc + col];
                if (ACT == ACT_RELU)       v = fmaxf(v, 0.f);
                else if (ACT == ACT_ELU)   v = v > 0.f ? v : expm1f(v);
                else if (ACT == ACT_LEAKY) v = v > 0.f ? v : 0.01f * v;
                if (OUT16) C16[(size_t)row * Nc + col] = f2bf(v);
                else       C32[(size_t)row * Nc + col] = v;
            }
        }
    }
}

__device__ __forceinline__ float wave_reduce_sum(float v)
{
    #pragma unroll
    for (int o = 32; o > 0; o >>= 1) v += __shfl_xor(v, o, 64);
    return v;
}
__device__ __forceinline__ float g32sum(float v)
{
    #pragma unroll
    for (int o = 16; o > 0; o >>= 1) v += __shfl_xor(v, o, 64);
    return v;
}

// ---------------- fp32 -> bf16 convert ----------------
__global__ __launch_bounds__(256)
void cvt16(const float* __restrict__ in, ushort* __restrict__ out, long n)
{
    long i = ((long)blockIdx.x * 256 + threadIdx.x) * 4;
    if (i >= n) return;
    float4 v = *(const float4*)&in[i];
    ushort4 o;
    o.x = f2bf(v.x); o.y = f2bf(v.y); o.z = f2bf(v.z); o.w = f2bf(v.w);
    *(ushort4*)&out[i] = o;
}

// ---------------- Wqk = Wq@Wk^T, bqk = bq@Wk^T -> Wcat cols 288..383 (fp32) ----------
__global__ __launch_bounds__(256)
void wqk_k(const float* __restrict__ Wq, const float* __restrict__ Wk,
           const float* __restrict__ bq, float* __restrict__ Wcat, float* __restrict__ bcat)
{
    int l = blockIdx.y;
    int idx = blockIdx.x * 256 + threadIdx.x;
    const float* wq = Wq + (size_t)l * DD * DD;
    const float* wk = Wk + (size_t)l * DD * DD;
    if (idx < DD * DD) {
        int k = idx / DD, j = idx % DD;
        float s = 0.f;
        for (int t = 0; t < DD; t++) s += wq[k * DD + t] * wk[j * DD + t];
        Wcat[(size_t)l * DD * 4 * DD + (size_t)k * 4 * DD + 288 + j] = s;
    }
    if (idx < DD) {
        int j = idx;
        float s = 0.f;
        for (int t = 0; t < DD; t++) s += bq[l * DD + t] * wk[j * DD + t];
        bcat[l * 4 * DD + 288 + j] = s;
    }
}

// ---------------- pack [Wq|Wk|Wv] into Wcat cols 0..287 + biases (fp32) ----------------
__global__ __launch_bounds__(256)
void pack_k(const float* __restrict__ Wq, const float* __restrict__ Wk,
            const float* __restrict__ Wv, const float* __restrict__ bq,
            const float* __restrict__ bk, const float* __restrict__ bv,
            float* __restrict__ Wcat, float* __restrict__ bcat)
{
    int idx = blockIdx.x * 256 + threadIdx.x;
    if (idx >= NLAYERS * DD * 288) return;
    int l = idx / (DD * 288);
    int rem = idx % (DD * 288);
    int k = rem / 288, n = rem % 288;
    int which = n / DD, j = n % DD;
    const float* W = which == 0 ? Wq : (which == 1 ? Wk : Wv);
    Wcat[(size_t)l * DD * 4 * DD + (size_t)k * 4 * DD + n] =
        W[(size_t)l * DD * DD + k * DD + j];
    if (k == 0) {
        const float* bb = which == 0 ? bq : (which == 1 ? bk : bv);
        bcat[l * 4 * DD + n] = bb[l * DD + j];
    }
}

// ---------------- transpose+convert all weights: src KxN fp32 -> dst NxK bf16 ----------
#define NPACK 22
struct PackArgs {
    const float* src[NPACK];
    ushort* dst[NPACK];
    int K[NPACK], N[NPACK];
};
__global__ __launch_bounds__(256)
void packT_k(PackArgs pa)
{
    int w = blockIdx.y;
    int K = pa.K[w], N = pa.N[w];
    int idx = blockIdx.x * 256 + threadIdx.x;
    if (idx >= K * N) return;
    int n = idx / K, k = idx % K;           // write-coalesced
    pa.dst[w][(size_t)n * K + k] = f2bf(pa.src[w][(size_t)k * N + n]);
}

// ---------------- adjacency build (padded slots) ----------------
__global__ __launch_bounds__(256)
void scatter_k(const int* __restrict__ src, const int* __restrict__ dst,
               int* __restrict__ deg, int2* __restrict__ pe)
{
    int e = blockIdx.x * 256 + threadIdx.x;
    if (e >= N_EDGES) return;
    int d = dst[e];
    int c = atomicAdd(&deg[d], 1);
    if (c < MAXDEG) pe[(size_t)d * MAXDEG + c] = make_int2(src[e], e);
}

// qkv16 row layout (bf16, stride 384): [0:96]=Q [96:192]=K [192:288]=V [288:384]=Qk
// All vectors consumed as bf16 pairs: lane holds dims {2*lane, 2*lane+1}, and
// lanes 0..15 additionally {64+2*lane, 65+2*lane}.
template<bool EA16>
__global__ __launch_bounds__(256)
void edge1b(const ushort* __restrict__ qkv16, const void* __restrict__ eaP,
            const int2* __restrict__ pe, const int* __restrict__ deg,
            float* __restrict__ ae_slot, float* __restrict__ denom, float scale)
{
    int grp = threadIdx.x >> 5, lane = threadIdx.x & 31;
    int d = blockIdx.x * 8 + grp;
    if (d >= N_NODES) return;
    const uint* qrow = (const uint*)(qkv16 + (size_t)d * 384);
    const uint* prow = (const uint*)(qkv16 + (size_t)d * 384 + 288);
    uint qu0 = qrow[lane];
    uint qu1 = (lane < 16) ? qrow[32 + lane] : 0u;
    uint pu0 = prow[lane];
    uint pu1 = (lane < 16) ? prow[32 + lane] : 0u;
    float q00 = bf_lo(qu0), q01 = bf_hi(qu0), q10 = bf_lo(qu1), q11 = bf_hi(qu1);
    float p00 = bf_lo(pu0), p01 = bf_hi(pu0), p10 = bf_lo(pu1), p11 = bf_hi(pu1);
    int2 pr0 = pe[(size_t)d * MAXDEG + lane];
    int2 pr1 = pe[(size_t)d * MAXDEG + 32 + lane];
    int cnt = deg[d]; if (cnt > MAXDEG) cnt = MAXDEG;
    for (int c = 0; c < cnt; c++) {
        int sx = __shfl(c < 32 ? pr0.x : pr1.x, c & 31, 32);
        int ex = __shfl(c < 32 ? pr0.y : pr1.y, c & 31, 32);
        const uint* krow = (const uint*)(qkv16 + (size_t)sx * 384 + 96);
        uint ku0 = krow[lane];
        float dot = q00 * bf_lo(ku0) + q01 * bf_hi(ku0);
        if (lane < 16) {
            uint ku1 = krow[32 + lane];
            dot += q10 * bf_lo(ku1) + q11 * bf_hi(ku1);
        }
        float e00, e01, e10 = 0.f, e11 = 0.f;
        if (EA16) {
            const uint* er = (const uint*)eaP + (size_t)ex * 48;
            uint eu0 = er[lane]; e00 = bf_lo(eu0); e01 = bf_hi(eu0);
            if (lane < 16) { uint eu1 = er[32 + lane]; e10 = bf_lo(eu1); e11 = bf_hi(eu1); }
        } else {
            const float* er = (const float*)eaP + (size_t)ex * DD;
            float2 ef0 = *(const float2*)&er[2 * lane]; e00 = ef0.x; e01 = ef0.y;
            if (lane < 16) { float2 ef1 = *(const float2*)&er[64 + 2 * lane]; e10 = ef1.x; e11 = ef1.y; }
        }
        dot += p00 * e00 + p01 * e01 + p10 * e10 + p11 * e11;
        dot = g32sum(dot);
        if (lane == 0) {
            float v = __expf(dot * scale);
            ae_slot[(size_t)d * MAXDEG + c] = v;
            atomicAdd(&denom[sx], v);
        }
    }
}

__global__ __launch_bounds__(256)
void recip_k(float* __restrict__ d)
{
    int i = blockIdx.x * 256 + threadIdx.x;
    if (i < N_NODES) d[i] = 1.f / d[i];
}

template<bool EA16>
__global__ __launch_bounds__(256)
void edge2b(const ushort* __restrict__ qkv16, const void* __restrict__ eaP,
            const float* __restrict__ ae_slot, const float* __restrict__ dinv,
            const int2* __restrict__ pe, const int* __restrict__ deg,
            float* __restrict__ agg, ushort* __restrict__ T16)
{
    int grp = threadIdx.x >> 5, lane = threadIdx.x & 31;
    int d = blockIdx.x * 8 + grp;
    if (d >= N_NODES) return;
    int2 pr0 = pe[(size_t)d * MAXDEG + lane];
    int2 pr1 = pe[(size_t)d * MAXDEG + 32 + lane];
    float ar0 = ae_slot[(size_t)d * MAXDEG + lane];
    float ar1 = ae_slot[(size_t)d * MAXDEG + 32 + lane];
    int cnt = deg[d]; if (cnt > MAXDEG) cnt = MAXDEG;
    float a00 = 0.f, a01 = 0.f, a10 = 0.f, a11 = 0.f;
    float t00 = 0.f, t01 = 0.f, t10 = 0.f, t11 = 0.f;
    for (int c = 0; c < cnt; c++) {
        int sx = __shfl(c < 32 ? pr0.x : pr1.x, c & 31, 32);
        int ex = __shfl(c < 32 ? pr0.y : pr1.y, c & 31, 32);
        float ae = __shfl(c < 32 ? ar0 : ar1, c & 31, 32);
        float w = ae * dinv[sx];
        const uint* vrow = (const uint*)(qkv16 + (size_t)sx * 384 + 192);
        uint vu0 = vrow[lane];
        a00 += w * bf_lo(vu0); a01 += w * bf_hi(vu0);
        if (lane < 16) {
            uint vu1 = vrow[32 + lane];
            a10 += w * bf_lo(vu1); a11 += w * bf_hi(vu1);
        }
        float e00, e01, e10 = 0.f, e11 = 0.f;
        if (EA16) {
            const uint* er = (const uint*)eaP + (size_t)ex * 48;
            uint eu0 = er[lane]; e00 = bf_lo(eu0); e01 = bf_hi(eu0);
            if (lane < 16) { uint eu1 = er[32 + lane]; e10 = bf_lo(eu1); e11 = bf_hi(eu1); }
        } else {
            const float* er = (const float*)eaP + (size_t)ex * DD;
            float2 ef0 = *(const float2*)&er[2 * lane]; e00 = ef0.x; e01 = ef0.y;
            if (lane < 16) { float2 ef1 = *(const float2*)&er[64 + 2 * lane]; e10 = ef1.x; e11 = ef1.y; }
        }
        t00 += w * e00; t01 += w * e01; t10 += w * e10; t11 += w * e11;
    }
    *(float2*)&agg[(size_t)d * DD + 2 * lane] = make_float2(a00, a01);
    ((uint*)T16)[(size_t)d * 48 + lane] = ((uint)f2bf(t01) << 16) | f2bf(t00);
    if (lane < 16) {
        *(float2*)&agg[(size_t)d * DD + 64 + 2 * lane] = make_float2(a10, a11);
        ((uint*)T16)[(size_t)d * 48 + 32 + lane] = ((uint)f2bf(t11) << 16) | f2bf(t10);
    }
}

// ---------------- LayerNorm: out16 = LN(a16 (+b)) * g + beta ----------------
// BMODE: 0 = no b, 1 = b fp32, 2 = b bf16
template<int RL, int BMODE>
__global__ __launch_bounds__(256)
void ln_b(const ushort* __restrict__ a, const void* __restrict__ bP,
          const float* __restrict__ g, const float* __restrict__ beta,
          ushort* __restrict__ out, int M)
{
    int wave = threadIdx.x >> 6;
    int lane = threadIdx.x & 63;
    int row = blockIdx.x * 4 + wave;
    if (row >= M) return;
    const int NE = (RL + 63) / 64;
    float vals[NE];
    float s = 0.f;
    #pragma unroll
    for (int i = 0; i < NE; i++) {
        int j = lane + i * 64;
        float x = 0.f;
        if (j < RL) {
            x = bfs(a[(size_t)row * RL + j]);
            if (BMODE == 1) x += ((const float*)bP)[(size_t)row * RL + j];
            if (BMODE == 2) x += bfs(((const ushort*)bP)[(size_t)row * RL + j]);
        }
        vals[i] = x; s += x;
    }
    s = wave_reduce_sum(s);
    float mean = s / RL;
    float sq = 0.f;
    #pragma unroll
    for (int i = 0; i < NE; i++) {
        int j = lane + i * 64;
        if (j < RL) { float dd = vals[i] - mean; sq += dd * dd; }
    }
    sq = wave_reduce_sum(sq);
    float rstd = rsqrtf(sq / RL + 1e-5f);
    #pragma unroll
    for (int i = 0; i < NE; i++) {
        int j = lane + i * 64;
        if (j < RL)
            out[(size_t)row * RL + j] = f2bf((vals[i] - mean) * rstd * g[j] + beta[j]);
    }
}

// ---------------- mean-pool scatter (bf16 in) ----------------
__global__ __launch_bounds__(256)
void pool_k(const ushort* __restrict__ u, const int* __restrict__ batch,
            float* __restrict__ pooled, float* __restrict__ cnt)
{
    int n = blockIdx.x * 4 + (threadIdx.x >> 6);
    int lane = threadIdx.x & 63;
    if (n >= N_NODES) return;
    int bg = batch[n];
    #pragma unroll
    for (int i = 0; i < 6; i++) {
        int j = lane + i * 64;
        atomicAdd(&pooled[(size_t)bg * HH + j], bfs(u[(size_t)n * HH + j]));
    }
    if (lane == 0) atomicAdd(&cnt[bg], 1.f);
}

// ---------------- classifier head ----------------
__global__ __launch_bounds__(64)
void clf_k(const float* __restrict__ pooled, const float* __restrict__ cnt,
           const float* __restrict__ W, const float* __restrict__ bcl,
           float* __restrict__ out)
{
    int g = blockIdx.x;
    int lane = threadIdx.x;
    float c = cnt[g]; c = c > 1.f ? c : 1.f;
    float inv = 1.f / c;
    float a0 = 0.f, a1 = 0.f;
    #pragma unroll
    for (int i = 0; i < 6; i++) {
        int j = lane + i * 64;
        float pv = pooled[(size_t)g * HH + j] * inv;
        a0 += pv * W[j * 2 + 0];
        a1 += pv * W[j * 2 + 1];
    }
    a0 = wave_reduce_sum(a0);
    a1 = wave_reduce_sum(a1);
    if (lane == 0) {
        out[g * 2 + 0] = a0 + bcl[0];
        out[g * 2 + 1] = a1 + bcl[1];
    }
}

extern "C" void kernel_launch(void* const* d_in, const int* in_sizes, int n_in,
                              void* d_out, int out_size, void* d_ws, size_t ws_size,
                              hipStream_t stream)
{
    const float* x       = (const float*)d_in[0];
    const float* ea      = (const float*)d_in[1];
    const float* emb_W1  = (const float*)d_in[2];
    const float* emb_b1  = (const float*)d_in[3];
    const float* emb_W2  = (const float*)d_in[4];
    const float* emb_b2  = (const float*)d_in[5];
    const float* Wq      = (const float*)d_in[6];
    const float* Wk      = (const float*)d_in[7];
    const float* Wv      = (const float*)d_in[8];
    const float* ffn_W1  = (const float*)d_in[9];
    const float* ffn_W2  = (const float*)d_in[10];
    const float* bq      = (const float*)d_in[11];
    const float* bk      = (const float*)d_in[12];
    const float* bv      = (const float*)d_in[13];
    const float* ffn_b1  = (const float*)d_in[14];
    const float* ffn_b2  = (const float*)d_in[15];
    const float* n1_b    = (const float*)d_in[16];
    const float* n2_b    = (const float*)d_in[17];
    const float* n1_g    = (const float*)d_in[18];
    const float* n2_g    = (const float*)d_in[19];
    const float* u_W1    = (const float*)d_in[20];
    const float* u_b1    = (const float*)d_in[21];
    const float* u_W2    = (const float*)d_in[22];
    const float* u_b2    = (const float*)d_in[23];
    const float* u_g     = (const float*)d_in[24];
    const float* u_bb    = (const float*)d_in[25];
    const float* clf_W   = (const float*)d_in[26];
    const float* clf_b   = (const float*)d_in[27];
    const float* rec_W1  = (const float*)d_in[28];
    const float* rec_b1  = (const float*)d_in[29];
    const float* rec_W2  = (const float*)d_in[30];
    const float* rec_b2  = (const float*)d_in[31];
    const int* edge_index = (const int*)d_in[32];
    const int* batch     = (const int*)d_in[33];
    const int* srcI = edge_index;
    const int* dstI = edge_index + N_EDGES;

    float* out   = (float*)d_out;
    float* r_out = out + NGRAPH * NOUT_;

    // ---- workspace bump allocator (256B aligned) ----
    char* base = (char*)d_ws;
    size_t off = 0;
    auto alloc = [&](size_t bytes) -> char* {
        char* r = base + off;
        off += (bytes + 255) & ~(size_t)255;
        return r;
    };
    ushort* h16     = (ushort*)alloc((size_t)N_NODES * DD * 2);
    ushort* qkv16   = (ushort*)alloc((size_t)N_NODES * HH * 2);
    float*  agg     = (float*) alloc((size_t)N_NODES * DD * 4);   // agg,T16,h116 contiguous
    ushort* T16     = (ushort*)alloc((size_t)N_NODES * DD * 2);
    ushort* h116    = (ushort*)alloc((size_t)N_NODES * DD * 2);
    int2*   pe      = (int2*)  alloc((size_t)N_NODES * MAXDEG * 8); // pe,ae_slot contiguous
    float*  ae_slot = (float*) alloc((size_t)N_NODES * MAXDEG * 4);
    ushort* f116    = (ushort*)alloc((size_t)N_NODES * DD * 2);
    float*  denom   = (float*) alloc((size_t)N_NODES * 4);
    int*    deg     = (int*)   alloc((size_t)N_NODES * 4);
    float*  pooled  = (float*) alloc((size_t)NGRAPH * HH * 4);
    float*  cnt     = (float*) alloc(NGRAPH * 4);
    float*  Wcat    = (float*) alloc((size_t)NLAYERS * DD * 4 * DD * 4);
    float*  bcat    = (float*) alloc((size_t)NLAYERS * 4 * DD * 4);
    ushort* x16     = (ushort*)alloc((size_t)N_NODES * INF_ * 2);
    ushort* embW1T  = (ushort*)alloc((size_t)HH * INF_ * 2);
    ushort* embW2T  = (ushort*)alloc((size_t)DD * HH * 2);
    ushort* WcatT   = (ushort*)alloc((size_t)NLAYERS * HH * DD * 2);
    ushort* WvT     = (ushort*)alloc((size_t)NLAYERS * DD * DD * 2);
    ushort* fW1T    = (ushort*)alloc((size_t)NLAYERS * DD * DD * 2);
    ushort* fW2T    = (ushort*)alloc((size_t)NLAYERS * DD * DD * 2);
    ushort* uW1T    = (ushort*)alloc((size_t)HH * DD * 2);
    ushort* uW2T    = (ushort*)alloc((size_t)HH * HH * 2);
    ushort* recW1T  = (ushort*)alloc((size_t)HH * HH * 2);
    ushort* recW2T  = (ushort*)alloc((size_t)INF_ * HH * 2);
    size_t base_need = off;
    ushort* ea16 = (ushort*)alloc((size_t)N_EDGES * DD * 2);
    bool use_ea16 = (ws_size >= off);
    const void* eaP = use_ea16 ? (const void*)ea16 : (const void*)ea;
    (void)base_need;

    // head-phase aliases (layer buffers dead)
    ushort* t16    = qkv16;                 // 38.4 MB
    ushort* upre16 = (ushort*)agg;          // spans agg+T16+h116 = 38.4 MB
    ushort* u16    = (ushort*)pe;           // spans pe+ae_slot = 38.4 MB
    ushort* rtmp16 = qkv16;                 // t16 dead after u2

    dim3 blk(256);
    const int GB = (N_NODES + 127) / 128;   // 391
    const float scale = 1.f / sqrtf((float)DD);

    // ---- weight precompute/pack ----
    wqk_k<<<dim3(36, NLAYERS), blk, 0, stream>>>(Wq, Wk, bq, Wcat, bcat);
    pack_k<<<(NLAYERS * DD * 288 + 255) / 256, blk, 0, stream>>>(
        Wq, Wk, Wv, bq, bk, bv, Wcat, bcat);
    PackArgs pa;
    int pi = 0;
    auto addp = [&](const float* s, ushort* d, int K, int N) {
        pa.src[pi] = s; pa.dst[pi] = d; pa.K[pi] = K; pa.N[pi] = N; pi++;
    };
    addp(emb_W1, embW1T, INF_, HH);
    addp(emb_W2, embW2T, HH, DD);
    for (int l = 0; l < NLAYERS; l++) addp(Wcat + (size_t)l * DD * 4 * DD, WcatT + (size_t)l * HH * DD, DD, HH);
    for (int l = 0; l < NLAYERS; l++) addp(Wv + (size_t)l * DD * DD, WvT + (size_t)l * DD * DD, DD, DD);
    for (int l = 0; l < NLAYERS; l++) addp(ffn_W1 + (size_t)l * DD * DD, fW1T + (size_t)l * DD * DD, DD, DD);
    for (int l = 0; l < NLAYERS; l++) addp(ffn_W2 + (size_t)l * DD * DD, fW2T + (size_t)l * DD * DD, DD, DD);
    addp(u_W1, uW1T, DD, HH);
    addp(u_W2, uW2T, HH, HH);
    addp(rec_W1, recW1T, HH, HH);
    addp(rec_W2, recW2T, HH, INF_);
    packT_k<<<dim3(576, NPACK), blk, 0, stream>>>(pa);

    // ---- input converts ----
    cvt16<<<((size_t)N_NODES * INF_ / 4 + 255) / 256, blk, 0, stream>>>(
        x, x16, (long)N_NODES * INF_);
    if (use_ea16)
        cvt16<<<((size_t)N_EDGES * DD / 4 + 255) / 256, blk, 0, stream>>>(
            ea, ea16, (long)N_EDGES * DD);

    // ---- atom embedding MLP ----
    gemm_mf<128, ACT_RELU, false, true><<<dim3(GB, 3), blk, 0, stream>>>(
        x16, embW1T, emb_b1, nullptr, t16, N_NODES, HH, INF_);
    gemm_mf<96, ACT_NONE, false, true><<<dim3(GB, 1), blk, 0, stream>>>(
        t16, embW2T, emb_b2, nullptr, h16, N_NODES, DD, HH);

    // ---- adjacency build ----
    hipMemsetAsync(deg, 0, N_NODES * sizeof(int), stream);
    scatter_k<<<(N_EDGES + 255) / 256, blk, 0, stream>>>(srcI, dstI, deg, pe);

    // ---- RPETConv layers ----
    for (int l = 0; l < NLAYERS; l++) {
        gemm_mf<128, ACT_NONE, false, true><<<dim3(GB, 3), blk, 0, stream>>>(
            h16, WcatT + (size_t)l * HH * DD, bcat + (size_t)l * 4 * DD,
            nullptr, qkv16, N_NODES, HH, DD);

        hipMemsetAsync(denom, 0, N_NODES * sizeof(float), stream);
        if (use_ea16) {
            edge1b<true><<<(N_NODES + 7) / 8, blk, 0, stream>>>(
                qkv16, eaP, pe, deg, ae_slot, denom, scale);
        } else {
            edge1b<false><<<(N_NODES + 7) / 8, blk, 0, stream>>>(
                qkv16, eaP, pe, deg, ae_slot, denom, scale);
        }
        recip_k<<<(N_NODES + 255) / 256, blk, 0, stream>>>(denom);
        if (use_ea16) {
            edge2b<true><<<(N_NODES + 7) / 8, blk, 0, stream>>>(
                qkv16, eaP, ae_slot, denom, pe, deg, agg, T16);
        } else {
            edge2b<false><<<(N_NODES + 7) / 8, blk, 0, stream>>>(
                qkv16, eaP, ae_slot, denom, pe, deg, agg, T16);
        }

        // agg += T @ Wv
        gemm_mf<96, ACT_NONE, true, false><<<dim3(GB, 1), blk, 0, stream>>>(
            T16, WvT + (size_t)l * DD * DD, nullptr, agg, nullptr, N_NODES, DD, DD);

        ln_b<DD, 1><<<(N_NODES + 3) / 4, blk, 0, stream>>>(
            h16, agg, n1_g + (size_t)l * DD, n1_b + (size_t)l * DD, h116, N_NODES);

        gemm_mf<96, ACT_ELU, false, true><<<dim3(GB, 1), blk, 0, stream>>>(
            h116, fW1T + (size_t)l * DD * DD, ffn_b1 + (size_t)l * DD,
            nullptr, f116, N_NODES, DD, DD);
        gemm_mf<96, ACT_NONE, false, true><<<dim3(GB, 1), blk, 0, stream>>>(
            f116, fW2T + (size_t)l * DD * DD, ffn_b2 + (size_t)l * DD,
            nullptr, T16, N_NODES, DD, DD);   // T16 dead -> reuse as f2 buffer
        ln_b<DD, 2><<<(N_NODES + 3) / 4, blk, 0, stream>>>(
            T16, h116, n2_g + (size_t)l * DD, n2_b + (size_t)l * DD, h16, N_NODES);
    }

    // ---- updim + LN ----
    gemm_mf<128, ACT_LEAKY, false, true><<<dim3(GB, 3), blk, 0, stream>>>(
        h16, uW1T, u_b1, nullptr, t16, N_NODES, HH, DD);
    gemm_mf<128, ACT_NONE, false, true><<<dim3(GB, 3), blk, 0, stream>>>(
        t16, uW2T, u_b2, nullptr, upre16, N_NODES, HH, HH);
    ln_b<HH, 0><<<(N_NODES + 3) / 4, blk, 0, stream>>>(
        upre16, nullptr, u_g, u_bb, u16, N_NODES);

    // ---- mean pool + classifier ----
    hipMemsetAsync(pooled, 0, (size_t)(NGRAPH * HH + NGRAPH) * sizeof(float), stream);
    pool_k<<<(N_NODES + 3) / 4, blk, 0, stream>>>(u16, batch, pooled, cnt);
    clf_k<<<NGRAPH, 64, 0, stream>>>(pooled, cnt, clf_W, clf_b, out);

    // ---- reconstruction head ----
    gemm_mf<128, ACT_RELU, false, true><<<dim3(GB, 3), blk, 0, stream>>>(
        u16, recW1T, rec_b1, nullptr, rtmp16, N_NODES, HH, HH);
    gemm_mf<64, ACT_NONE, false, false><<<dim3(GB, 1), blk, 0, stream>>>(
        rtmp16, recW2T, rec_b2, r_out, nullptr, N_NODES, INF_, HH);
}

// Round 5
// 1781.305 us; speedup vs baseline: 2.5582x; 1.1439x over previous
//
#include <hip/hip_runtime.h>
#include <math.h>

#define N_NODES 50000
#define N_EDGES 640000
#define INF_ 64
#define DD 96
#define HH 384
#define NLAYERS 4
#define NGRAPH 512
#define NOUT_ 2
#define MAXDEG 64

#define ACT_NONE 0
#define ACT_RELU 1
#define ACT_ELU 2
#define ACT_LEAKY 3

typedef unsigned int uint;
typedef unsigned short ushort;
typedef __attribute__((ext_vector_type(8))) short v8s;   // 8 bf16 (4 VGPRs)
typedef __attribute__((ext_vector_type(4))) float v4f;   // 4 fp32 acc

__device__ __forceinline__ float bf_lo(uint u) { return __uint_as_float(u << 16); }
__device__ __forceinline__ float bf_hi(uint u) { return __uint_as_float(u & 0xffff0000u); }
__device__ __forceinline__ float bfs(ushort s) { return __uint_as_float(((uint)s) << 16); }
__device__ __forceinline__ ushort f2bf(float f)
{
    uint u = __float_as_uint(f);
    return (ushort)((u + 0x7fffu + ((u >> 16) & 1u)) >> 16);
}

// ================= MFMA bf16 GEMM: C = act(A@B (+bias) (+C)) =================
// A: M x K bf16 row-major. Bt: N x K bf16 row-major (pre-transposed weights).
// BM=128, 256 thr = 4 waves (2x2), wave tile 64 x BN/2. K % 32 == 0, Nc % BN == 0.
template<int BN, int ACT, bool ACCUM, bool OUT16>
__global__ __launch_bounds__(256)
void gemm_mf(const ushort* __restrict__ A, const ushort* __restrict__ Bt,
             const float* __restrict__ bias, float* __restrict__ C32,
             ushort* __restrict__ C16, int M, int Nc, int K)
{
    const int BM = 128, LDA = 40;      // 32 + 8 pad (bf16 units) -> 2-way b128, free
    const int FN = BN / 32;            // n-fragments per wave
    __shared__ ushort As[BM * LDA];
    __shared__ ushort Bs[BN * LDA];
    int tid = threadIdx.x;
    int lane = tid & 63, wave = tid >> 6;
    int ln15 = lane & 15, quad = lane >> 4;
    int wm = (wave >> 1) * 64, wn = (wave & 1) * (BN / 2);
    int bm0 = blockIdx.x * BM, bn0 = blockIdx.y * BN;

    v4f acc[4][FN];
    #pragma unroll
    for (int i = 0; i < 4; i++)
        #pragma unroll
        for (int j = 0; j < FN; j++) acc[i][j] = (v4f){0.f, 0.f, 0.f, 0.f};

    for (int k0 = 0; k0 < K; k0 += 32) {
        #pragma unroll
        for (int it = 0; it < 2; it++) {
            int u = it * 256 + tid;
            int r = u >> 2, c8 = (u & 3) * 8;
            int row = bm0 + r;
            int4 v = make_int4(0, 0, 0, 0);
            if (row < M) v = *(const int4*)&A[(size_t)row * K + k0 + c8];
            *(int4*)&As[r * LDA + c8] = v;
        }
        #pragma unroll
        for (int it = 0; it < (BN * 4 + 255) / 256; it++) {
            int u = it * 256 + tid;
            if ((BN * 4) % 256 == 0 || u < BN * 4) {
                int r = u >> 2, c8 = (u & 3) * 8;
                *(int4*)&Bs[r * LDA + c8] =
                    *(const int4*)&Bt[(size_t)(bn0 + r) * K + k0 + c8];
            }
        }
        __syncthreads();
        v8s af[4], bf[FN];
        #pragma unroll
        for (int i = 0; i < 4; i++)
            af[i] = *(const v8s*)&As[(wm + i * 16 + ln15) * LDA + quad * 8];
        #pragma unroll
        for (int j = 0; j < FN; j++)
            bf[j] = *(const v8s*)&Bs[(wn + j * 16 + ln15) * LDA + quad * 8];
        #pragma unroll
        for (int i = 0; i < 4; i++)
            #pragma unroll
            for (int j = 0; j < FN; j++)
                acc[i][j] = __builtin_amdgcn_mfma_f32_16x16x32_bf16(
                    af[i], bf[j], acc[i][j], 0, 0, 0);
        __syncthreads();
    }
    #pragma unroll
    for (int i = 0; i < 4; i++) {
        #pragma unroll
        for (int j = 0; j < FN; j++) {
            int col = bn0 + wn + j * 16 + ln15;
            float bsv = bias ? bias[col] : 0.f;
            #pragma unroll
            for (int r = 0; r < 4; r++) {
                int row = bm0 + wm + i * 16 + quad * 4 + r;
                if (row >= M) continue;
                float v = acc[i][j][r] + bsv;
                if (ACCUM) v += C32[(size_t)row * Nc + col];
                if (ACT == ACT_RELU)       v = fmaxf(v, 0.f);
                else if (ACT == ACT_ELU)   v = v > 0.f ? v : expm1f(v);
                else if (ACT == ACT_LEAKY) v = v > 0.f ? v : 0.01f * v;
                if (OUT16) C16[(size_t)row * Nc + col] = f2bf(v);
                else       C32[(size_t)row * Nc + col] = v;
            }
        }
    }
}

__device__ __forceinline__ float wave_reduce_sum(float v)
{
    #pragma unroll
    for (int o = 32; o > 0; o >>= 1) v += __shfl_xor(v, o, 64);
    return v;
}

// ---------------- fp32 -> bf16 convert ----------------
__global__ __launch_bounds__(256)
void cvt16(const float* __restrict__ in, ushort* __restrict__ out, long n)
{
    long i = ((long)blockIdx.x * 256 + threadIdx.x) * 4;
    if (i >= n) return;
    float4 v = *(const float4*)&in[i];
    ushort4 o;
    o.x = f2bf(v.x); o.y = f2bf(v.y); o.z = f2bf(v.z); o.w = f2bf(v.w);
    *(ushort4*)&out[i] = o;
}

// ---------------- Wqk = Wq@Wk^T, bqk = bq@Wk^T -> Wcat cols 288..383 (fp32) ----------
__global__ __launch_bounds__(256)
void wqk_k(const float* __restrict__ Wq, const float* __restrict__ Wk,
           const float* __restrict__ bq, float* __restrict__ Wcat, float* __restrict__ bcat)
{
    int l = blockIdx.y;
    int idx = blockIdx.x * 256 + threadIdx.x;
    const float* wq = Wq + (size_t)l * DD * DD;
    const float* wk = Wk + (size_t)l * DD * DD;
    if (idx < DD * DD) {
        int k = idx / DD, j = idx % DD;
        float s = 0.f;
        for (int t = 0; t < DD; t++) s += wq[k * DD + t] * wk[j * DD + t];
        Wcat[(size_t)l * DD * 4 * DD + (size_t)k * 4 * DD + 288 + j] = s;
    }
    if (idx < DD) {
        int j = idx;
        float s = 0.f;
        for (int t = 0; t < DD; t++) s += bq[l * DD + t] * wk[j * DD + t];
        bcat[l * 4 * DD + 288 + j] = s;
    }
}

// ---------------- pack [Wq|Wk|Wv] into Wcat cols 0..287 + biases (fp32) ----------------
__global__ __launch_bounds__(256)
void pack_k(const float* __restrict__ Wq, const float* __restrict__ Wk,
            const float* __restrict__ Wv, const float* __restrict__ bq,
            const float* __restrict__ bk, const float* __restrict__ bv,
            float* __restrict__ Wcat, float* __restrict__ bcat)
{
    int idx = blockIdx.x * 256 + threadIdx.x;
    if (idx >= NLAYERS * DD * 288) return;
    int l = idx / (DD * 288);
    int rem = idx % (DD * 288);
    int k = rem / 288, n = rem % 288;
    int which = n / DD, j = n % DD;
    const float* W = which == 0 ? Wq : (which == 1 ? Wk : Wv);
    Wcat[(size_t)l * DD * 4 * DD + (size_t)k * 4 * DD + n] =
        W[(size_t)l * DD * DD + k * DD + j];
    if (k == 0) {
        const float* bb = which == 0 ? bq : (which == 1 ? bk : bv);
        bcat[l * 4 * DD + n] = bb[l * DD + j];
    }
}

// ---------------- transpose+convert all weights: src KxN fp32 -> dst NxK bf16 ----------
#define NPACK 22
struct PackArgs {
    const float* src[NPACK];
    ushort* dst[NPACK];
    int K[NPACK], N[NPACK];
};
__global__ __launch_bounds__(256)
void packT_k(PackArgs pa)
{
    int w = blockIdx.y;
    int K = pa.K[w], N = pa.N[w];
    int idx = blockIdx.x * 256 + threadIdx.x;
    if (idx >= K * N) return;
    int n = idx / K, k = idx % K;           // write-coalesced
    pa.dst[w][(size_t)n * K + k] = f2bf(pa.src[w][(size_t)k * N + n]);
}

// ---------------- adjacency build (padded slots) ----------------
__global__ __launch_bounds__(256)
void scatter_k(const int* __restrict__ src, const int* __restrict__ dst,
               int* __restrict__ deg, int2* __restrict__ pe)
{
    int e = blockIdx.x * 256 + threadIdx.x;
    if (e >= N_EDGES) return;
    int d = dst[e];
    int c = atomicAdd(&deg[d], 1);
    if (c < MAXDEG) pe[(size_t)d * MAXDEG + c] = make_int2(src[e], e);
}

// qkv16 row layout (bf16, stride 384): [0:96]=Q [96:192]=K [192:288]=V [288:384]=Qk
// One 64-lane wave per dst node; halves (lanes 0-31 / 32-63) process two edges
// concurrently, unrolled x2 -> 4 edges in flight per wave.
template<bool EA16>
__global__ __launch_bounds__(256)
void edge1w(const ushort* __restrict__ qkv16, const void* __restrict__ eaP,
            const int2* __restrict__ pe, const int* __restrict__ deg,
            float* __restrict__ ae_slot, float* __restrict__ denom, float scale)
{
    int lane = threadIdx.x & 63;
    int half = lane >> 5, l32 = lane & 31;
    int d = blockIdx.x * 4 + (threadIdx.x >> 6);
    if (d >= N_NODES) return;
    int cnt = deg[d]; if (cnt > MAXDEG) cnt = MAXDEG;
    if (cnt == 0) return;
    const uint* qrow = (const uint*)(qkv16 + (size_t)d * 384);
    const uint* prow = (const uint*)(qkv16 + (size_t)d * 384 + 288);
    uint qu0 = qrow[l32], pu0 = prow[l32];
    uint qu1 = 0, pu1 = 0;
    if (l32 < 16) { qu1 = qrow[32 + l32]; pu1 = prow[32 + l32]; }
    float q00 = bf_lo(qu0), q01 = bf_hi(qu0), q10 = bf_lo(qu1), q11 = bf_hi(qu1);
    float p00 = bf_lo(pu0), p01 = bf_hi(pu0), p10 = bf_lo(pu1), p11 = bf_hi(pu1);
    int2 pr = pe[(size_t)d * MAXDEG + lane];
    for (int cb = 0; cb < cnt; cb += 4) {
        float dots[2];
        int sxu[2];
        #pragma unroll
        for (int u = 0; u < 2; u++) {
            int myc = cb + 2 * u + half;
            int cc = myc < cnt ? myc : cnt - 1;
            int sx = __shfl(pr.x, cc);
            int ex = __shfl(pr.y, cc);
            sxu[u] = sx;
            const uint* krow = (const uint*)(qkv16 + (size_t)sx * 384 + 96);
            uint ku0 = krow[l32];
            float e00, e01, e10 = 0.f, e11 = 0.f;
            uint ku1 = 0;
            if (EA16) {
                const uint* er = (const uint*)eaP + (size_t)ex * 48;
                uint eu0 = er[l32]; e00 = bf_lo(eu0); e01 = bf_hi(eu0);
                if (l32 < 16) {
                    uint eu1 = er[32 + l32]; e10 = bf_lo(eu1); e11 = bf_hi(eu1);
                    ku1 = krow[32 + l32];
                }
            } else {
                const float* er = (const float*)eaP + (size_t)ex * DD;
                float2 ef0 = *(const float2*)&er[2 * l32]; e00 = ef0.x; e01 = ef0.y;
                if (l32 < 16) {
                    float2 ef1 = *(const float2*)&er[64 + 2 * l32]; e10 = ef1.x; e11 = ef1.y;
                    ku1 = krow[32 + l32];
                }
            }
            float dot = q00 * bf_lo(ku0) + q01 * bf_hi(ku0)
                      + p00 * e00 + p01 * e01 + p10 * e10 + p11 * e11;
            if (l32 < 16) dot += q10 * bf_lo(ku1) + q11 * bf_hi(ku1);
            dots[u] = dot;
        }
        #pragma unroll
        for (int o = 16; o > 0; o >>= 1) {
            dots[0] += __shfl_xor(dots[0], o);
            dots[1] += __shfl_xor(dots[1], o);
        }
        #pragma unroll
        for (int u = 0; u < 2; u++) {
            int myc = cb + 2 * u + half;
            if (l32 == 0 && myc < cnt) {
                float v = __expf(dots[u] * scale);
                ae_slot[(size_t)d * MAXDEG + myc] = v;
                atomicAdd(&denom[sxu[u]], v);
            }
        }
    }
}

template<bool EA16>
__global__ __launch_bounds__(256)
void edge2w(const ushort* __restrict__ qkv16, const void* __restrict__ eaP,
            const float* __restrict__ ae_slot, const float* __restrict__ denom,
            const int2* __restrict__ pe, const int* __restrict__ deg,
            float* __restrict__ agg, ushort* __restrict__ T16)
{
    int lane = threadIdx.x & 63;
    int half = lane >> 5, l32 = lane & 31;
    int d = blockIdx.x * 4 + (threadIdx.x >> 6);
    if (d >= N_NODES) return;
    int cnt = deg[d]; if (cnt > MAXDEG) cnt = MAXDEG;
    int2 pr = pe[(size_t)d * MAXDEG + lane];
    float ar = ae_slot[(size_t)d * MAXDEG + lane];
    float a00 = 0.f, a01 = 0.f, a10 = 0.f, a11 = 0.f;
    float t00 = 0.f, t01 = 0.f, t10 = 0.f, t11 = 0.f;
    for (int cb = 0; cb < cnt; cb += 4) {
        #pragma unroll
        for (int u = 0; u < 2; u++) {
            int myc = cb + 2 * u + half;
            int cc = myc < cnt ? myc : cnt - 1;
            int sx = __shfl(pr.x, cc);
            int ex = __shfl(pr.y, cc);
            float ae = __shfl(ar, cc);
            float w = (myc < cnt) ? ae / denom[sx] : 0.f;
            const uint* vrow = (const uint*)(qkv16 + (size_t)sx * 384 + 192);
            uint vu0 = vrow[l32];
            float e00, e01, e10 = 0.f, e11 = 0.f;
            uint vu1 = 0;
            if (EA16) {
                const uint* er = (const uint*)eaP + (size_t)ex * 48;
                uint eu0 = er[l32]; e00 = bf_lo(eu0); e01 = bf_hi(eu0);
                if (l32 < 16) {
                    uint eu1 = er[32 + l32]; e10 = bf_lo(eu1); e11 = bf_hi(eu1);
                    vu1 = vrow[32 + l32];
                }
            } else {
                const float* er = (const float*)eaP + (size_t)ex * DD;
                float2 ef0 = *(const float2*)&er[2 * l32]; e00 = ef0.x; e01 = ef0.y;
                if (l32 < 16) {
                    float2 ef1 = *(const float2*)&er[64 + 2 * l32]; e10 = ef1.x; e11 = ef1.y;
                    vu1 = vrow[32 + l32];
                }
            }
            a00 += w * bf_lo(vu0); a01 += w * bf_hi(vu0);
            t00 += w * e00; t01 += w * e01;
            if (l32 < 16) {
                a10 += w * bf_lo(vu1); a11 += w * bf_hi(vu1);
                t10 += w * e10; t11 += w * e11;
            }
        }
    }
    // cross-half combine
    a00 += __shfl_xor(a00, 32); a01 += __shfl_xor(a01, 32);
    a10 += __shfl_xor(a10, 32); a11 += __shfl_xor(a11, 32);
    t00 += __shfl_xor(t00, 32); t01 += __shfl_xor(t01, 32);
    t10 += __shfl_xor(t10, 32); t11 += __shfl_xor(t11, 32);
    if (half == 0) {
        *(float2*)&agg[(size_t)d * DD + 2 * l32] = make_float2(a00, a01);
        ((uint*)T16)[(size_t)d * 48 + l32] = ((uint)f2bf(t01) << 16) | f2bf(t00);
        if (l32 < 16) {
            *(float2*)&agg[(size_t)d * DD + 64 + 2 * l32] = make_float2(a10, a11);
            ((uint*)T16)[(size_t)d * 48 + 32 + l32] = ((uint)f2bf(t11) << 16) | f2bf(t10);
        }
    }
}

// ---------------- LayerNorm: out16 = LN(a16 (+b)) * g + beta ----------------
// BMODE: 0 = no b, 1 = b fp32, 2 = b bf16
template<int RL, int BMODE>
__global__ __launch_bounds__(256)
void ln_b(const ushort* __restrict__ a, const void* __restrict__ bP,
          const float* __restrict__ g, const float* __restrict__ beta,
          ushort* __restrict__ out, int M)
{
    int wave = threadIdx.x >> 6;
    int lane = threadIdx.x & 63;
    int row = blockIdx.x * 4 + wave;
    if (row >= M) return;
    const int NE = (RL + 63) / 64;
    float vals[NE];
    float s = 0.f;
    #pragma unroll
    for (int i = 0; i < NE; i++) {
        int j = lane + i * 64;
        float x = 0.f;
        if (j < RL) {
            x = bfs(a[(size_t)row * RL + j]);
            if (BMODE == 1) x += ((const float*)bP)[(size_t)row * RL + j];
            if (BMODE == 2) x += bfs(((const ushort*)bP)[(size_t)row * RL + j]);
        }
        vals[i] = x; s += x;
    }
    s = wave_reduce_sum(s);
    float mean = s / RL;
    float sq = 0.f;
    #pragma unroll
    for (int i = 0; i < NE; i++) {
        int j = lane + i * 64;
        if (j < RL) { float dd = vals[i] - mean; sq += dd * dd; }
    }
    sq = wave_reduce_sum(sq);
    float rstd = rsqrtf(sq / RL + 1e-5f);
    #pragma unroll
    for (int i = 0; i < NE; i++) {
        int j = lane + i * 64;
        if (j < RL)
            out[(size_t)row * RL + j] = f2bf((vals[i] - mean) * rstd * g[j] + beta[j]);
    }
}

// ---------------- mean-pool scatter (bf16 in) ----------------
__global__ __launch_bounds__(256)
void pool_k(const ushort* __restrict__ u, const int* __restrict__ batch,
            float* __restrict__ pooled, float* __restrict__ cnt)
{
    int n = blockIdx.x * 4 + (threadIdx.x >> 6);
    int lane = threadIdx.x & 63;
    if (n >= N_NODES) return;
    int bg = batch[n];
    #pragma unroll
    for (int i = 0; i < 6; i++) {
        int j = lane + i * 64;
        atomicAdd(&pooled[(size_t)bg * HH + j], bfs(u[(size_t)n * HH + j]));
    }
    if (lane == 0) atomicAdd(&cnt[bg], 1.f);
}

// ---------------- classifier head ----------------
__global__ __launch_bounds__(64)
void clf_k(const float* __restrict__ pooled, const float* __restrict__ cnt,
           const float* __restrict__ W, const float* __restrict__ bcl,
           float* __restrict__ out)
{
    int g = blockIdx.x;
    int lane = threadIdx.x;
    float c = cnt[g]; c = c > 1.f ? c : 1.f;
    float inv = 1.f / c;
    float a0 = 0.f, a1 = 0.f;
    #pragma unroll
    for (int i = 0; i < 6; i++) {
        int j = lane + i * 64;
        float pv = pooled[(size_t)g * HH + j] * inv;
        a0 += pv * W[j * 2 + 0];
        a1 += pv * W[j * 2 + 1];
    }
    a0 = wave_reduce_sum(a0);
    a1 = wave_reduce_sum(a1);
    if (lane == 0) {
        out[g * 2 + 0] = a0 + bcl[0];
        out[g * 2 + 1] = a1 + bcl[1];
    }
}

extern "C" void kernel_launch(void* const* d_in, const int* in_sizes, int n_in,
                              void* d_out, int out_size, void* d_ws, size_t ws_size,
                              hipStream_t stream)
{
    const float* x       = (const float*)d_in[0];
    const float* ea      = (const float*)d_in[1];
    const float* emb_W1  = (const float*)d_in[2];
    const float* emb_b1  = (const float*)d_in[3];
    const float* emb_W2  = (const float*)d_in[4];
    const float* emb_b2  = (const float*)d_in[5];
    const float* Wq      = (const float*)d_in[6];
    const float* Wk      = (const float*)d_in[7];
    const float* Wv      = (const float*)d_in[8];
    const float* ffn_W1  = (const float*)d_in[9];
    const float* ffn_W2  = (const float*)d_in[10];
    const float* bq      = (const float*)d_in[11];
    const float* bk      = (const float*)d_in[12];
    const float* bv      = (const float*)d_in[13];
    const float* ffn_b1  = (const float*)d_in[14];
    const float* ffn_b2  = (const float*)d_in[15];
    const float* n1_b    = (const float*)d_in[16];
    const float* n2_b    = (const float*)d_in[17];
    const float* n1_g    = (const float*)d_in[18];
    const float* n2_g    = (const float*)d_in[19];
    const float* u_W1    = (const float*)d_in[20];
    const float* u_b1    = (const float*)d_in[21];
    const float* u_W2    = (const float*)d_in[22];
    const float* u_b2    = (const float*)d_in[23];
    const float* u_g     = (const float*)d_in[24];
    const float* u_bb    = (const float*)d_in[25];
    const float* clf_W   = (const float*)d_in[26];
    const float* clf_b   = (const float*)d_in[27];
    const float* rec_W1  = (const float*)d_in[28];
    const float* rec_b1  = (const float*)d_in[29];
    const float* rec_W2  = (const float*)d_in[30];
    const float* rec_b2  = (const float*)d_in[31];
    const int* edge_index = (const int*)d_in[32];
    const int* batch     = (const int*)d_in[33];
    const int* srcI = edge_index;
    const int* dstI = edge_index + N_EDGES;

    float* out   = (float*)d_out;
    float* r_out = out + NGRAPH * NOUT_;

    // ---- workspace bump allocator (256B aligned) ----
    char* base = (char*)d_ws;
    size_t off = 0;
    auto alloc = [&](size_t bytes) -> char* {
        char* r = base + off;
        off += (bytes + 255) & ~(size_t)255;
        return r;
    };
    ushort* h16     = (ushort*)alloc((size_t)N_NODES * DD * 2);
    ushort* qkv16   = (ushort*)alloc((size_t)N_NODES * HH * 2);
    float*  agg     = (float*) alloc((size_t)N_NODES * DD * 4);   // agg,T16,h116 contiguous
    ushort* T16     = (ushort*)alloc((size_t)N_NODES * DD * 2);
    ushort* h116    = (ushort*)alloc((size_t)N_NODES * DD * 2);
    int2*   pe      = (int2*)  alloc((size_t)N_NODES * MAXDEG * 8); // pe,ae_slot contiguous
    float*  ae_slot = (float*) alloc((size_t)N_NODES * MAXDEG * 4);
    ushort* f116    = (ushort*)alloc((size_t)N_NODES * DD * 2);
    float*  denom   = (float*) alloc((size_t)N_NODES * 4);
    int*    deg     = (int*)   alloc((size_t)N_NODES * 4);
    float*  pooled  = (float*) alloc((size_t)NGRAPH * HH * 4);
    float*  cnt     = (float*) alloc(NGRAPH * 4);
    float*  Wcat    = (float*) alloc((size_t)NLAYERS * DD * 4 * DD * 4);
    float*  bcat    = (float*) alloc((size_t)NLAYERS * 4 * DD * 4);
    ushort* x16     = (ushort*)alloc((size_t)N_NODES * INF_ * 2);
    ushort* embW1T  = (ushort*)alloc((size_t)HH * INF_ * 2);
    ushort* embW2T  = (ushort*)alloc((size_t)DD * HH * 2);
    ushort* WcatT   = (ushort*)alloc((size_t)NLAYERS * HH * DD * 2);
    ushort* WvT     = (ushort*)alloc((size_t)NLAYERS * DD * DD * 2);
    ushort* fW1T    = (ushort*)alloc((size_t)NLAYERS * DD * DD * 2);
    ushort* fW2T    = (ushort*)alloc((size_t)NLAYERS * DD * DD * 2);
    ushort* uW1T    = (ushort*)alloc((size_t)HH * DD * 2);
    ushort* uW2T    = (ushort*)alloc((size_t)HH * HH * 2);
    ushort* recW1T  = (ushort*)alloc((size_t)HH * HH * 2);
    ushort* recW2T  = (ushort*)alloc((size_t)INF_ * HH * 2);
    ushort* ea16 = (ushort*)alloc((size_t)N_EDGES * DD * 2);
    bool use_ea16 = (ws_size >= off);
    const void* eaP = use_ea16 ? (const void*)ea16 : (const void*)ea;

    // head-phase aliases (layer buffers dead)
    ushort* t16    = qkv16;                 // 38.4 MB
    ushort* upre16 = (ushort*)agg;          // spans agg+T16+h116 = 38.4 MB
    ushort* u16    = (ushort*)pe;           // spans pe+ae_slot = 38.4 MB
    ushort* rtmp16 = qkv16;                 // t16 dead after u2

    dim3 blk(256);
    const int GB = (N_NODES + 127) / 128;   // 391
    const float scale = 1.f / sqrtf((float)DD);

    // ---- weight precompute/pack ----
    wqk_k<<<dim3(36, NLAYERS), blk, 0, stream>>>(Wq, Wk, bq, Wcat, bcat);
    pack_k<<<(NLAYERS * DD * 288 + 255) / 256, blk, 0, stream>>>(
        Wq, Wk, Wv, bq, bk, bv, Wcat, bcat);
    PackArgs pa;
    int pi = 0;
    auto addp = [&](const float* s, ushort* d, int K, int N) {
        pa.src[pi] = s; pa.dst[pi] = d; pa.K[pi] = K; pa.N[pi] = N; pi++;
    };
    addp(emb_W1, embW1T, INF_, HH);
    addp(emb_W2, embW2T, HH, DD);
    for (int l = 0; l < NLAYERS; l++) addp(Wcat + (size_t)l * DD * 4 * DD, WcatT + (size_t)l * HH * DD, DD, HH);
    for (int l = 0; l < NLAYERS; l++) addp(Wv + (size_t)l * DD * DD, WvT + (size_t)l * DD * DD, DD, DD);
    for (int l = 0; l < NLAYERS; l++) addp(ffn_W1 + (size_t)l * DD * DD, fW1T + (size_t)l * DD * DD, DD, DD);
    for (int l = 0; l < NLAYERS; l++) addp(ffn_W2 + (size_t)l * DD * DD, fW2T + (size_t)l * DD * DD, DD, DD);
    addp(u_W1, uW1T, DD, HH);
    addp(u_W2, uW2T, HH, HH);
    addp(rec_W1, recW1T, HH, HH);
    addp(rec_W2, recW2T, HH, INF_);
    packT_k<<<dim3(576, NPACK), blk, 0, stream>>>(pa);

    // ---- input converts ----
    cvt16<<<((size_t)N_NODES * INF_ / 4 + 255) / 256, blk, 0, stream>>>(
        x, x16, (long)N_NODES * INF_);
    if (use_ea16)
        cvt16<<<((size_t)N_EDGES * DD / 4 + 255) / 256, blk, 0, stream>>>(
            ea, ea16, (long)N_EDGES * DD);

    // ---- atom embedding MLP ----
    gemm_mf<128, ACT_RELU, false, true><<<dim3(GB, 3), blk, 0, stream>>>(
        x16, embW1T, emb_b1, nullptr, t16, N_NODES, HH, INF_);
    gemm_mf<96, ACT_NONE, false, true><<<dim3(GB, 1), blk, 0, stream>>>(
        t16, embW2T, emb_b2, nullptr, h16, N_NODES, DD, HH);

    // ---- adjacency build ----
    hipMemsetAsync(deg, 0, N_NODES * sizeof(int), stream);
    scatter_k<<<(N_EDGES + 255) / 256, blk, 0, stream>>>(srcI, dstI, deg, pe);

    // ---- RPETConv layers ----
    const int EGRID = (N_NODES + 3) / 4;
    for (int l = 0; l < NLAYERS; l++) {
        gemm_mf<128, ACT_NONE, false, true><<<dim3(GB, 3), blk, 0, stream>>>(
            h16, WcatT + (size_t)l * HH * DD, bcat + (size_t)l * 4 * DD,
            nullptr, qkv16, N_NODES, HH, DD);

        hipMemsetAsync(denom, 0, N_NODES * sizeof(float), stream);
        if (use_ea16) {
            edge1w<true><<<EGRID, blk, 0, stream>>>(
                qkv16, eaP, pe, deg, ae_slot, denom, scale);
            edge2w<true><<<EGRID, blk, 0, stream>>>(
                qkv16, eaP, ae_slot, denom, pe, deg, agg, T16);
        } else {
            edge1w<false><<<EGRID, blk, 0, stream>>>(
                qkv16, eaP, pe, deg, ae_slot, denom, scale);
            edge2w<false><<<EGRID, blk, 0, stream>>>(
                qkv16, eaP, ae_slot, denom, pe, deg, agg, T16);
        }

        // agg += T @ Wv
        gemm_mf<96, ACT_NONE, true, false><<<dim3(GB, 1), blk, 0, stream>>>(
            T16, WvT + (size_t)l * DD * DD, nullptr, agg, nullptr, N_NODES, DD, DD);

        ln_b<DD, 1><<<(N_NODES + 3) / 4, blk, 0, stream>>>(
            h16, agg, n1_g + (size_t)l * DD, n1_b + (size_t)l * DD, h116, N_NODES);

        gemm_mf<96, ACT_ELU, false, true><<<dim3(GB, 1), blk, 0, stream>>>(
            h116, fW1T + (size_t)l * DD * DD, ffn_b1 + (size_t)l * DD,
            nullptr, f116, N_NODES, DD, DD);
        gemm_mf<96, ACT_NONE, false, true><<<dim3(GB, 1), blk, 0, stream>>>(
            f116, fW2T + (size_t)l * DD * DD, ffn_b2 + (size_t)l * DD,
            nullptr, T16, N_NODES, DD, DD);   // T16 dead -> reuse as f2 buffer
        ln_b<DD, 2><<<(N_NODES + 3) / 4, blk, 0, stream>>>(
            T16, h116, n2_g + (size_t)l * DD, n2_b + (size_t)l * DD, h16, N_NODES);
    }

    // ---- updim + LN ----
    gemm_mf<128, ACT_LEAKY, false, true><<<dim3(GB, 3), blk, 0, stream>>>(
        h16, uW1T, u_b1, nullptr, t16, N_NODES, HH, DD);
    gemm_mf<128, ACT_NONE, false, true><<<dim3(GB, 3), blk, 0, stream>>>(
        t16, uW2T, u_b2, nullptr, upre16, N_NODES, HH, HH);
    ln_b<HH, 0><<<(N_NODES + 3) / 4, blk, 0, stream>>>(
        upre16, nullptr, u_g, u_bb, u16, N_NODES);

    // ---- mean pool + classifier ----
    hipMemsetAsync(pooled, 0, (size_t)(NGRAPH * HH + NGRAPH) * sizeof(float), stream);
    pool_k<<<(N_NODES + 3) / 4, blk, 0, stream>>>(u16, batch, pooled, cnt);
    clf_k<<<NGRAPH, 64, 0, stream>>>(pooled, cnt, clf_W, clf_b, out);

    // ---- reconstruction head ----
    gemm_mf<128, ACT_RELU, false, true><<<dim3(GB, 3), blk, 0, stream>>>(
        u16, recW1T, rec_b1, nullptr, rtmp16, N_NODES, HH, HH);
    gemm_mf<64, ACT_NONE, false, false><<<dim3(GB, 1), blk, 0, stream>>>(
        rtmp16, recW2T, rec_b2, r_out, nullptr, N_NODES, INF_, HH);
}